// Round 1
// baseline (62739.252 us; speedup 1.0000x reference)
//
#include <hip/hip_runtime.h>

// DecoderModule: B=64, T=128, S=512, E=256, H=512, 2H=1024, GRU_IN=1280
// Persistent-kernel version: the whole 128-step recurrence runs inside ONE
// kernel (512 blocks x 256 thr, 2 blocks/CU co-resident via __launch_bounds__)
// with a two-level device-scope grid barrier between phases. Removes ~640
// kernel-launch boundaries that dominated the 6.0 ms baseline.

#define LDSS 40  // padded LDS row stride in shorts (80B = 5*16B)

typedef short bf16x8 __attribute__((ext_vector_type(8)));
typedef float f32x4 __attribute__((ext_vector_type(4)));

__device__ inline ushort f2b(float f) {
    unsigned int u = __float_as_uint(f);
    return (ushort)((u + 0x7FFFu + ((u >> 16) & 1u)) >> 16);
}
__device__ inline float b2f(ushort u) {
    return __uint_as_float(((unsigned int)u) << 16);
}
__device__ inline float fast_tanh(float x) {
    x = fminf(fmaxf(x, -15.f), 15.f);
    float ex = __expf(2.f * x);
    return (ex - 1.f) / (ex + 1.f);
}

__global__ void f2b4_kernel(const float4* __restrict__ in, ushort4* __restrict__ out, int n4) {
    int i = blockIdx.x * blockDim.x + threadIdx.x;
    int stride = gridDim.x * blockDim.x;
    for (; i < n4; i += stride) {
        float4 v = in[i];
        ushort4 o;
        o.x = f2b(v.x); o.y = f2b(v.y); o.z = f2b(v.z); o.w = f2b(v.w);
        out[i] = o;
    }
}

// ---------------------------------------------------------------------------
// 64x64 MFMA bf16 NT-GEMM tile over K range [kbeg,kend):
// C[m,n] (+)= sum_k A[m,k]*B[n,k]. B bf16 [N,K]; A bf16 or fp32 [M,K].
// ATOMIC: atomicAdd into fp32 C (K-split). Else plain store fp32/bf16.
// ---------------------------------------------------------------------------
template <bool AF32, bool ATOMIC>
__device__ inline void gemm64x64(const void* __restrict__ Av,
                                 const ushort* __restrict__ B,
                                 ushort* As, ushort* Bs,
                                 int lda, int ldb, int kbeg, int kend,
                                 float* Cf, ushort* Cb, long ldc,
                                 long m0, long n0)
{
    const int tid  = threadIdx.x;
    const int wave = tid >> 6;
    const int lane = tid & 63;
    const int row  = tid >> 2;
    const int kcol = (tid & 3) * 8;
    const int lrow = lane & 15;
    const int quad = lane >> 4;

    f32x4 acc[4];
#pragma unroll
    for (int i = 0; i < 4; i++) acc[i] = f32x4{0.f, 0.f, 0.f, 0.f};

    const ushort* Ab  = (const ushort*)Av + (m0 + row) * (long)lda + kcol;
    const float*  Afp = (const float*)Av + (m0 + row) * (long)lda + kcol;
    const ushort* Bp  = B + (n0 + row) * (long)ldb + kcol;
    ushort* AsW = As + row * LDSS + kcol;
    ushort* BsW = Bs + row * LDSS + kcol;
    const ushort* AsR = As + (wave * 16 + lrow) * LDSS + quad * 8;
    const ushort* BsR = Bs + lrow * LDSS + quad * 8;

    for (int k0 = kbeg; k0 < kend; k0 += 32) {
        uint4 av;
        if (AF32) {
            float4 f0 = *(const float4*)(Afp + k0);
            float4 f1 = *(const float4*)(Afp + k0 + 4);
            av.x = (uint)f2b(f0.x) | ((uint)f2b(f0.y) << 16);
            av.y = (uint)f2b(f0.z) | ((uint)f2b(f0.w) << 16);
            av.z = (uint)f2b(f1.x) | ((uint)f2b(f1.y) << 16);
            av.w = (uint)f2b(f1.z) | ((uint)f2b(f1.w) << 16);
        } else {
            av = *(const uint4*)(Ab + k0);
        }
        uint4 bv = *(const uint4*)(Bp + k0);
        __syncthreads();
        *(uint4*)AsW = av;
        *(uint4*)BsW = bv;
        __syncthreads();
        bf16x8 af = *(const bf16x8*)AsR;
#pragma unroll
        for (int nf = 0; nf < 4; nf++) {
            bf16x8 bfv = *(const bf16x8*)(BsR + nf * 16 * LDSS);
            acc[nf] = __builtin_amdgcn_mfma_f32_16x16x32_bf16(af, bfv, acc[nf], 0, 0, 0);
        }
    }

#pragma unroll
    for (int nf = 0; nf < 4; nf++) {
#pragma unroll
        for (int r = 0; r < 4; r++) {
            long m = m0 + wave * 16 + quad * 4 + r;
            long n = n0 + nf * 16 + lrow;
            float v = acc[nf][r];
            if (ATOMIC)      atomicAdd(&Cf[m * ldc + n], v);
            else if (Cf)     Cf[m * ldc + n] = v;
            else             Cb[m * ldc + n] = f2b(v);
        }
    }
}

template <bool AF32>
__global__ void gemm_nt(const void* __restrict__ A, const ushort* __restrict__ B,
                        float* Cf, ushort* Cb,
                        int lda, int ldb, long ldc, int K, int nTilesN)
{
    __shared__ ushort As[64 * LDSS];
    __shared__ ushort Bs[64 * LDSS];
    long m0 = (long)(blockIdx.x / nTilesN) * 64;
    long n0 = (long)(blockIdx.x % nTilesN) * 64;
    gemm64x64<AF32, false>(A, B, As, Bs, lda, ldb, 0, K, Cf, Cb, ldc, m0, n0);
}

// ---------------------------------------------------------------------------
// Two-level grid barrier. bar[0..7]=group counters (64 blocks each),
// bar[8]=group-done, bar[12]=generation, bar[13]=fail flag.
// Timeout -> fail flag -> all later barriers fall through (wrong result, no hang).
// ---------------------------------------------------------------------------
__device__ inline void gridbar(int* bar) {
    __syncthreads();
    if (threadIdx.x == 0) {
        int* gen  = bar + 12;
        int* fail = bar + 13;
        if (__hip_atomic_load(fail, __ATOMIC_RELAXED, __HIP_MEMORY_SCOPE_AGENT) == 0) {
            int g0 = __hip_atomic_load(gen, __ATOMIC_RELAXED, __HIP_MEMORY_SCOPE_AGENT);
            __threadfence();  // publish this block's stores (L2 writeback)
            int grp = blockIdx.x & 7;
            int my = __hip_atomic_fetch_add(bar + grp, 1, __ATOMIC_ACQ_REL, __HIP_MEMORY_SCOPE_AGENT);
            if (my == 63) {
                __hip_atomic_store(bar + grp, 0, __ATOMIC_RELAXED, __HIP_MEMORY_SCOPE_AGENT);
                int md = __hip_atomic_fetch_add(bar + 8, 1, __ATOMIC_ACQ_REL, __HIP_MEMORY_SCOPE_AGENT);
                if (md == 7) {
                    __hip_atomic_store(bar + 8, 0, __ATOMIC_RELAXED, __HIP_MEMORY_SCOPE_AGENT);
                    __hip_atomic_fetch_add(gen, 1, __ATOMIC_RELEASE, __HIP_MEMORY_SCOPE_AGENT);
                }
            }
            int polls = 0;
            while (__hip_atomic_load(gen, __ATOMIC_ACQUIRE, __HIP_MEMORY_SCOPE_AGENT) == g0) {
                __builtin_amdgcn_s_sleep(2);
                if (++polls > (1 << 19)) {
                    __hip_atomic_store(fail, 1, __ATOMIC_RELAXED, __HIP_MEMORY_SCOPE_AGENT);
                    break;
                }
            }
            __threadfence();  // invalidate stale caches before next phase's reads
        }
    }
    __syncthreads();
}

struct LP {
    const ushort* pk; const ushort* Wq; const ushort* Whh; const ushort* Wpre; const ushort* Wih;
    const float* wE; const int* mask; const float* trg; const float* enc; const ushort* enc_b;
    float* q; float* gh; float* gx; float* e;
    ushort* xcat; ushort* cat2; ushort* h_b; float* h;
    const float* bih; const float* bhh;
    float* d_states; float* out_pre;
    int* bar; int useb;
};

// ---------------------------------------------------------------------------
// Persistent kernel: 512 blocks x 256 threads, 2 blocks/CU co-resident.
// Per step: A(q GEMM) | B(e + gh + pre(t-1)) | C(softmax+ctx) | D(gx) | E(gates)
// with grid barriers between. Phase internals identical to the proven
// standalone kernels (same K-splits, same atomic accumulation + re-zeroing).
// ---------------------------------------------------------------------------
__global__ void __launch_bounds__(256, 2) loop_kernel(LP P)
{
    __shared__ float smem[2592];   // 10368 B: GEMM As/Bs (10240) or sc alpha/wred/part (10256)
    ushort* As = (ushort*)smem;
    ushort* Bs = As + 64 * LDSS;
    const int bid  = blockIdx.x;
    const int tid  = threadIdx.x;
    const int lane = tid & 63;

    for (int t = 0; t < 128; t++) {
        // ---- phase A: q = h @ Wq^T (16 blocks, K-split 2x256) ----
        if (bid < 16) {
            int kc = bid >> 3, nt = bid & 7;
            gemm64x64<false, true>(P.h_b, P.Wq, As, Bs, 512, 512, kc * 256, kc * 256 + 256,
                                   P.q, nullptr, 512, 0, (long)nt * 64);
        }
        gridbar(P.bar);

        // ---- phase B: e (432 blocks) + gh (48 blocks) + pre(t-1) (32 blocks) ----
        if (bid < 432) {
            int wid = (bid << 2) + (tid >> 6);           // 0..1727
            const float* wp = P.wE + lane * 8;
            float4 w0 = *(const float4*)wp, w1 = *(const float4*)(wp + 4);
            int task = wid;                               // task = b*512 + s, < 32768
            bf16x8 pv = *(const bf16x8*)(P.pk + ((long)task << 9) + lane * 8);
            while (1) {
                int nx = task + 1728;
                bool more = nx < 32768;
                bf16x8 pn;
                if (more) pn = *(const bf16x8*)(P.pk + ((long)nx << 9) + lane * 8);
                const float* qp = P.q + ((long)(task >> 9) << 9) + lane * 8;
                float4 q0 = *(const float4*)qp, q1 = *(const float4*)(qp + 4);
                float acc;
                acc  = fast_tanh(q0.x + b2f((ushort)pv[0])) * w0.x;
                acc += fast_tanh(q0.y + b2f((ushort)pv[1])) * w0.y;
                acc += fast_tanh(q0.z + b2f((ushort)pv[2])) * w0.z;
                acc += fast_tanh(q0.w + b2f((ushort)pv[3])) * w0.w;
                acc += fast_tanh(q1.x + b2f((ushort)pv[4])) * w1.x;
                acc += fast_tanh(q1.y + b2f((ushort)pv[5])) * w1.y;
                acc += fast_tanh(q1.z + b2f((ushort)pv[6])) * w1.z;
                acc += fast_tanh(q1.w + b2f((ushort)pv[7])) * w1.w;
#pragma unroll
                for (int off = 32; off; off >>= 1) acc += __shfl_xor(acc, off);
                if (lane == 0) P.e[task] = (P.mask[task] != 0) ? acc : -1e9f;
                if (!more) break;
                pv = pn; task = nx;
            }
        } else if (bid < 480) {
            int b3 = bid - 432, kc = b3 / 24, nt = b3 % 24;
            gemm64x64<false, true>(P.h_b, P.Whh, As, Bs, 512, 512, kc * 256, kc * 256 + 256,
                                   P.gh, nullptr, 1536, 0, (long)nt * 64);
        } else if (t > 0) {
            int b4 = bid - 480, kc = b4 >> 3, nt = b4 & 7;
            gemm64x64<false, true>(P.cat2, P.Wpre, As, Bs, 1792, 1792, kc * 448, kc * 448 + 448,
                                   P.out_pre + (long)(t - 1) * 512, nullptr, 65536, 0, (long)nt * 64);
        }
        gridbar(P.bar);

        // ---- phase C: softmax + context. block -> (b = bid>>3, dc = 2*(bid&7)+{0,1}) ----
        {
            int b   = bid >> 3;
            int dc0 = (bid & 7) << 1;
            float* alpha = smem;            // 512
            float* wred  = smem + 512;      // 4
            float* part  = smem + 516;      // 2048
            float p0 = __expf(P.e[(b << 9) + tid]);        // masked -1e9 -> 0
            float p1 = __expf(P.e[(b << 9) + 256 + tid]);
            alpha[tid] = p0; alpha[tid + 256] = p1;
            float wsum = p0 + p1;
#pragma unroll
            for (int off = 32; off; off >>= 1) wsum += __shfl_xor(wsum, off);
            if (lane == 0) wred[tid >> 6] = wsum;
            __syncthreads();
            float inv = 1.f / (wred[0] + wred[1] + wred[2] + wred[3]);
            if (P.useb) {
                int dg = tid & 7, sp = tid >> 3;
#pragma unroll
                for (int half = 0; half < 2; half++) {
                    int dc = dc0 + half;
                    const ushort* pb = P.enc_b + ((long)b << 19) + (dc << 6) + dg * 8;
                    float a0=0.f,a1=0.f,a2=0.f,a3=0.f,a4=0.f,a5=0.f,a6=0.f,a7=0.f;
                    for (int s = sp; s < 512; s += 32) {
                        bf16x8 v = *(const bf16x8*)(pb + ((long)s << 10));
                        float al = alpha[s];
                        a0 += al * b2f((ushort)v[0]);
                        a1 += al * b2f((ushort)v[1]);
                        a2 += al * b2f((ushort)v[2]);
                        a3 += al * b2f((ushort)v[3]);
                        a4 += al * b2f((ushort)v[4]);
                        a5 += al * b2f((ushort)v[5]);
                        a6 += al * b2f((ushort)v[6]);
                        a7 += al * b2f((ushort)v[7]);
                    }
                    float* pp = part + sp * 64 + dg * 8;
                    pp[0]=a0; pp[1]=a1; pp[2]=a2; pp[3]=a3;
                    pp[4]=a4; pp[5]=a5; pp[6]=a6; pp[7]=a7;
                    __syncthreads();
                    if (tid < 64) {
                        float ctx = 0.f;
#pragma unroll
                        for (int k = 0; k < 32; k++) ctx += part[k * 64 + tid];
                        ctx *= inv;
                        ushort cb = f2b(ctx);
                        int d = (dc << 6) + tid;
                        P.xcat[b * 1280 + 256 + d] = cb;
                        P.cat2[b * 1792 + 768 + d] = cb;
                    } else if (tid >= 128 && tid < 192 && dc < 4) {  // stage x_t (256/b)
                        int dl = tid - 128;
                        ushort xv = f2b(P.trg[((long)b * 128 + t) * 256 + (dc << 6) + dl]);
                        P.xcat[b * 1280 + (dc << 6) + dl] = xv;
                        P.cat2[b * 1792 + (dc << 6) + dl] = xv;
                    }
                    __syncthreads();
                }
            } else {
                int dl = lane, sr = tid >> 6;
#pragma unroll
                for (int half = 0; half < 2; half++) {
                    int dc = dc0 + half;
                    int d = (dc << 6) + dl;
                    const float* pf = P.enc + ((long)b << 19) + d;
                    float a0=0.f,a1=0.f,a2=0.f,a3=0.f;
                    for (int s = sr; s < 512; s += 16) {
                        a0 += alpha[s]      * pf[(long)s << 10];
                        a1 += alpha[s + 4]  * pf[(long)(s + 4) << 10];
                        a2 += alpha[s + 8]  * pf[(long)(s + 8) << 10];
                        a3 += alpha[s + 12] * pf[(long)(s + 12) << 10];
                    }
                    part[tid] = (a0 + a1) + (a2 + a3);
                    __syncthreads();
                    if (sr == 0) {
                        float ctx = (part[dl] + part[64 + dl] + part[128 + dl] + part[192 + dl]) * inv;
                        ushort cb = f2b(ctx);
                        P.xcat[b * 1280 + 256 + d] = cb;
                        P.cat2[b * 1792 + 768 + d] = cb;
                    } else if (sr == 1 && dc < 4) {
                        ushort xv = f2b(P.trg[((long)b * 128 + t) * 256 + (dc << 6) + dl]);
                        P.xcat[b * 1280 + (dc << 6) + dl] = xv;
                        P.cat2[b * 1792 + (dc << 6) + dl] = xv;
                    }
                    __syncthreads();
                }
            }
        }
        gridbar(P.bar);

        // ---- phase D: gx = [x_t, ctx] @ W_ih^T (96 blocks, K-split 4x320) ----
        if (bid < 96) {
            int nt = bid % 24, kc = bid / 24;
            gemm64x64<false, true>(P.xcat, P.Wih, As, Bs, 1280, 1280, kc * 320, kc * 320 + 320,
                                   P.gx, nullptr, 1536, 0, (long)nt * 64);
        }
        gridbar(P.bar);

        // ---- phase E: GRU gates + h update + re-zero accumulators ----
        if (bid < 128) {
            int idx = (bid << 8) + tid;
            int b = idx >> 9, j = idx & 511;
            float* gxp = P.gx + b * 1536;
            float* ghp = P.gh + b * 1536;
            float rx = gxp[j]        + P.bih[j];
            float zx = gxp[j + 512]  + P.bih[j + 512];
            float nx = gxp[j + 1024] + P.bih[j + 1024];
            float rh = ghp[j]        + P.bhh[j];
            float zh = ghp[j + 512]  + P.bhh[j + 512];
            float nh = ghp[j + 1024] + P.bhh[j + 1024];
            float r = 1.f / (1.f + __expf(-(rx + rh)));
            float z = 1.f / (1.f + __expf(-(zx + zh)));
            float n = fast_tanh(nx + r * nh);
            float hn = (1.f - z) * n + z * P.h[idx];
            P.h[idx] = hn;
            P.h_b[idx] = f2b(hn);
            P.cat2[b * 1792 + 256 + j] = f2b(hn);
            P.d_states[((long)b * 128 + t) * 512 + j] = hn;
            gxp[j] = 0.f; gxp[j + 512] = 0.f; gxp[j + 1024] = 0.f;
            ghp[j] = 0.f; ghp[j + 512] = 0.f; ghp[j + 1024] = 0.f;
            P.q[idx] = 0.f;
            P.out_pre[((long)b * 128 + t) * 512 + j] = 0.f;
        }
        gridbar(P.bar);
    }

    // final pre-output GEMM for slice t=127 (cat2 complete after step 127)
    if (bid < 32) {
        int kc = bid >> 3, nt = bid & 7;
        gemm64x64<false, true>(P.cat2, P.Wpre, As, Bs, 1792, 1792, kc * 448, kc * 448 + 448,
                               P.out_pre + (long)127 * 512, nullptr, 65536, 0, (long)nt * 64);
    }
}

// bridge tanh + zero-init all atomic accumulators and the grid barrier.
__global__ void btanh_kernel(const float* __restrict__ br, const float* __restrict__ bbr,
                             float* __restrict__ h, ushort* __restrict__ h_b,
                             float* __restrict__ q, float* __restrict__ gh,
                             float* __restrict__ gx, int* __restrict__ bar)
{
    int idx = blockIdx.x * blockDim.x + threadIdx.x;  // 0..32767
    if (idx < 16) bar[idx] = 0;
    int b = idx >> 9, j = idx & 511;
    float v = fast_tanh(br[idx] + bbr[j]);
    h[idx] = v;
    h_b[idx] = f2b(v);
    q[idx] = 0.f;
    gh[b * 1536 + j] = 0.f; gh[b * 1536 + j + 512] = 0.f; gh[b * 1536 + j + 1024] = 0.f;
    gx[b * 1536 + j] = 0.f; gx[b * 1536 + j + 512] = 0.f; gx[b * 1536 + j + 1024] = 0.f;
}

__global__ void hid_kernel(const float* __restrict__ h, float* __restrict__ out)
{
    int idx = blockIdx.x * blockDim.x + threadIdx.x;
    out[idx] = h[idx];
}

extern "C" void kernel_launch(void* const* d_in, const int* in_sizes, int n_in,
                              void* d_out, int out_size, void* d_ws, size_t ws_size,
                              hipStream_t stream)
{
    (void)in_sizes; (void)n_in; (void)out_size;
    const float* trg  = (const float*)d_in[0];
    const float* enc  = (const float*)d_in[1];
    const float* encF = (const float*)d_in[2];
    const int*   mask = (const int*)d_in[3];
    const float* Wkey = (const float*)d_in[4];
    const float* Wq   = (const float*)d_in[5];
    const float* wE   = (const float*)d_in[6];
    const float* Wbr  = (const float*)d_in[7];
    const float* bbr  = (const float*)d_in[8];
    const float* Wih  = (const float*)d_in[9];
    const float* Whh  = (const float*)d_in[10];
    const float* bih  = (const float*)d_in[11];
    const float* bhh  = (const float*)d_in[12];
    const float* Wpre = (const float*)d_in[13];

    char* p = (char*)d_ws;
    auto alloc = [&](size_t bytes) { void* r = (void*)p; p += (bytes + 255) & ~(size_t)255; return r; };
    ushort* pk     = (ushort*)alloc(16777216ul * 2);
    ushort* Wkey_b = (ushort*)alloc(524288ul * 2);
    ushort* Wq_b   = (ushort*)alloc(262144ul * 2);
    ushort* Wbr_b  = (ushort*)alloc(524288ul * 2);
    ushort* Wih_b  = (ushort*)alloc(1966080ul * 2);
    ushort* Whh_b  = (ushort*)alloc(786432ul * 2);
    ushort* Wpre_b = (ushort*)alloc(917504ul * 2);
    float*  h    = (float*)alloc(32768ul * 4);
    ushort* h_b  = (ushort*)alloc(32768ul * 2);
    float*  br   = (float*)alloc(32768ul * 4);
    float*  q    = (float*)alloc(32768ul * 4);
    float*  gh   = (float*)alloc(98304ul * 4);
    float*  gx   = (float*)alloc(98304ul * 4);
    float*  e    = (float*)alloc(32768ul * 4);
    ushort* xcat = (ushort*)alloc(81920ul * 2);
    ushort* cat2 = (ushort*)alloc(114688ul * 2);
    int*    bar  = (int*)alloc(64ul * 4);
    size_t used = (size_t)(p - (char*)d_ws);
    int useb = (used + 33554432ul * 2 <= ws_size) ? 1 : 0;
    ushort* enc_b = useb ? (ushort*)alloc(33554432ul * 2) : nullptr;

    float* out_states = (float*)d_out;
    float* out_hidden = out_states + 64l * 128 * 512;
    float* out_pre    = out_hidden + 64l * 512;

    f2b4_kernel<<<512, 256, 0, stream>>>((const float4*)Wkey, (ushort4*)Wkey_b, 131072);
    f2b4_kernel<<<256, 256, 0, stream>>>((const float4*)Wq,   (ushort4*)Wq_b,   65536);
    f2b4_kernel<<<512, 256, 0, stream>>>((const float4*)Wbr,  (ushort4*)Wbr_b,  131072);
    f2b4_kernel<<<1920, 256, 0, stream>>>((const float4*)Wih, (ushort4*)Wih_b,  491520);
    f2b4_kernel<<<768, 256, 0, stream>>>((const float4*)Whh,  (ushort4*)Whh_b,  196608);
    f2b4_kernel<<<896, 256, 0, stream>>>((const float4*)Wpre, (ushort4*)Wpre_b, 229376);

    if (useb) {
        f2b4_kernel<<<8192, 256, 0, stream>>>((const float4*)enc, (ushort4*)enc_b, 8388608);
        gemm_nt<false><<<4096, 256, 0, stream>>>(enc_b, Wkey_b, nullptr, pk, 1024, 1024, 512, 1024, 8);
    } else {
        gemm_nt<true><<<4096, 256, 0, stream>>>(enc, Wkey_b, nullptr, pk, 1024, 1024, 512, 1024, 8);
    }
    gemm_nt<true><<<8, 256, 0, stream>>>(encF, Wbr_b, br, nullptr, 1024, 1024, 512, 1024, 8);
    btanh_kernel<<<128, 256, 0, stream>>>(br, bbr, h, h_b, q, gh, gx, bar);

    LP P;
    P.pk = pk; P.Wq = Wq_b; P.Whh = Whh_b; P.Wpre = Wpre_b; P.Wih = Wih_b;
    P.wE = wE; P.mask = mask; P.trg = trg; P.enc = enc; P.enc_b = enc_b;
    P.q = q; P.gh = gh; P.gx = gx; P.e = e;
    P.xcat = xcat; P.cat2 = cat2; P.h_b = h_b; P.h = h;
    P.bih = bih; P.bhh = bhh;
    P.d_states = out_states; P.out_pre = out_pre;
    P.bar = bar; P.useb = useb;
    loop_kernel<<<512, 256, 0, stream>>>(P);

    hid_kernel<<<128, 256, 0, stream>>>(h, out_hidden);
}

// Round 2
// 30806.900 us; speedup vs baseline: 2.0365x; 2.0365x over previous
//
#include <hip/hip_runtime.h>

// DecoderModule: B=64, T=128, S=512, E=256, H=512, 2H=1024, GRU_IN=1280
// Persistent-kernel version: the whole 128-step recurrence runs inside ONE
// kernel (512 blocks x 256 thr, 2 blocks/CU co-resident) with a two-level
// grid barrier. Round-2 fix: barrier uses RELAXED system-scope atomics
// (no per-op cache maintenance) + ONE release/acquire agent fence pair per
// block per barrier. Round-1's per-poll ACQUIRE invalidates caused a TCC
// cache-op storm (94us/barrier, 60ms total).

#define LDSS 40  // padded LDS row stride in shorts (80B = 5*16B)

typedef short bf16x8 __attribute__((ext_vector_type(8)));
typedef float f32x4 __attribute__((ext_vector_type(4)));

__device__ inline ushort f2b(float f) {
    unsigned int u = __float_as_uint(f);
    return (ushort)((u + 0x7FFFu + ((u >> 16) & 1u)) >> 16);
}
__device__ inline float b2f(ushort u) {
    return __uint_as_float(((unsigned int)u) << 16);
}
__device__ inline float fast_tanh(float x) {
    x = fminf(fmaxf(x, -15.f), 15.f);
    float ex = __expf(2.f * x);
    return (ex - 1.f) / (ex + 1.f);
}

__global__ void f2b4_kernel(const float4* __restrict__ in, ushort4* __restrict__ out, int n4) {
    int i = blockIdx.x * blockDim.x + threadIdx.x;
    int stride = gridDim.x * blockDim.x;
    for (; i < n4; i += stride) {
        float4 v = in[i];
        ushort4 o;
        o.x = f2b(v.x); o.y = f2b(v.y); o.z = f2b(v.z); o.w = f2b(v.w);
        out[i] = o;
    }
}

// ---------------------------------------------------------------------------
// 64x64 MFMA bf16 NT-GEMM tile over K range [kbeg,kend):
// C[m,n] (+)= sum_k A[m,k]*B[n,k]. B bf16 [N,K]; A bf16 or fp32 [M,K].
// ATOMIC: atomicAdd into fp32 C (K-split). Else plain store fp32/bf16.
// ---------------------------------------------------------------------------
template <bool AF32, bool ATOMIC>
__device__ inline void gemm64x64(const void* __restrict__ Av,
                                 const ushort* __restrict__ B,
                                 ushort* As, ushort* Bs,
                                 int lda, int ldb, int kbeg, int kend,
                                 float* Cf, ushort* Cb, long ldc,
                                 long m0, long n0)
{
    const int tid  = threadIdx.x;
    const int wave = tid >> 6;
    const int lane = tid & 63;
    const int row  = tid >> 2;
    const int kcol = (tid & 3) * 8;
    const int lrow = lane & 15;
    const int quad = lane >> 4;

    f32x4 acc[4];
#pragma unroll
    for (int i = 0; i < 4; i++) acc[i] = f32x4{0.f, 0.f, 0.f, 0.f};

    const ushort* Ab  = (const ushort*)Av + (m0 + row) * (long)lda + kcol;
    const float*  Afp = (const float*)Av + (m0 + row) * (long)lda + kcol;
    const ushort* Bp  = B + (n0 + row) * (long)ldb + kcol;
    ushort* AsW = As + row * LDSS + kcol;
    ushort* BsW = Bs + row * LDSS + kcol;
    const ushort* AsR = As + (wave * 16 + lrow) * LDSS + quad * 8;
    const ushort* BsR = Bs + lrow * LDSS + quad * 8;

    for (int k0 = kbeg; k0 < kend; k0 += 32) {
        uint4 av;
        if (AF32) {
            float4 f0 = *(const float4*)(Afp + k0);
            float4 f1 = *(const float4*)(Afp + k0 + 4);
            av.x = (uint)f2b(f0.x) | ((uint)f2b(f0.y) << 16);
            av.y = (uint)f2b(f0.z) | ((uint)f2b(f0.w) << 16);
            av.z = (uint)f2b(f1.x) | ((uint)f2b(f1.y) << 16);
            av.w = (uint)f2b(f1.z) | ((uint)f2b(f1.w) << 16);
        } else {
            av = *(const uint4*)(Ab + k0);
        }
        uint4 bv = *(const uint4*)(Bp + k0);
        __syncthreads();
        *(uint4*)AsW = av;
        *(uint4*)BsW = bv;
        __syncthreads();
        bf16x8 af = *(const bf16x8*)AsR;
#pragma unroll
        for (int nf = 0; nf < 4; nf++) {
            bf16x8 bfv = *(const bf16x8*)(BsR + nf * 16 * LDSS);
            acc[nf] = __builtin_amdgcn_mfma_f32_16x16x32_bf16(af, bfv, acc[nf], 0, 0, 0);
        }
    }

#pragma unroll
    for (int nf = 0; nf < 4; nf++) {
#pragma unroll
        for (int r = 0; r < 4; r++) {
            long m = m0 + wave * 16 + quad * 4 + r;
            long n = n0 + nf * 16 + lrow;
            float v = acc[nf][r];
            if (ATOMIC)      atomicAdd(&Cf[m * ldc + n], v);
            else if (Cf)     Cf[m * ldc + n] = v;
            else             Cb[m * ldc + n] = f2b(v);
        }
    }
}

template <bool AF32>
__global__ void gemm_nt(const void* __restrict__ A, const ushort* __restrict__ B,
                        float* Cf, ushort* Cb,
                        int lda, int ldb, long ldc, int K, int nTilesN)
{
    __shared__ ushort As[64 * LDSS];
    __shared__ ushort Bs[64 * LDSS];
    long m0 = (long)(blockIdx.x / nTilesN) * 64;
    long n0 = (long)(blockIdx.x % nTilesN) * 64;
    gemm64x64<AF32, false>(A, B, As, Bs, lda, ldb, 0, K, Cf, Cb, ldc, m0, n0);
}

// ---------------------------------------------------------------------------
// Two-level grid barrier. bar[0..7]=group counters (64 blocks each),
// bar[8]=group-done, bar[12]=generation, bar[13]=fail flag.
// All counter ops RELAXED at SYSTEM scope (bypass caches, no maintenance).
// Exactly one release fence before arrival and one acquire fence after the
// generation flip. Timeout -> fail flag -> later barriers fall through.
// ---------------------------------------------------------------------------
__device__ inline void gridbar(int* bar) {
    __syncthreads();
    if (threadIdx.x == 0) {
        int* gen  = bar + 12;
        int* fail = bar + 13;
        if (__hip_atomic_load(fail, __ATOMIC_RELAXED, __HIP_MEMORY_SCOPE_SYSTEM) == 0) {
            int g0 = __hip_atomic_load(gen, __ATOMIC_RELAXED, __HIP_MEMORY_SCOPE_SYSTEM);
            __builtin_amdgcn_fence(__ATOMIC_RELEASE, "agent");  // publish phase stores (wb L2, once)
            int grp = blockIdx.x & 7;
            int my = __hip_atomic_fetch_add(bar + grp, 1, __ATOMIC_RELAXED, __HIP_MEMORY_SCOPE_SYSTEM);
            if (my == 63) {
                __hip_atomic_store(bar + grp, 0, __ATOMIC_RELAXED, __HIP_MEMORY_SCOPE_SYSTEM);
                int md = __hip_atomic_fetch_add(bar + 8, 1, __ATOMIC_RELAXED, __HIP_MEMORY_SCOPE_SYSTEM);
                if (md == 7) {
                    __hip_atomic_store(bar + 8, 0, __ATOMIC_RELAXED, __HIP_MEMORY_SCOPE_SYSTEM);
                    __hip_atomic_store(gen, g0 + 1, __ATOMIC_RELAXED, __HIP_MEMORY_SCOPE_SYSTEM);
                }
            }
            int polls = 0;
            while (__hip_atomic_load(gen, __ATOMIC_RELAXED, __HIP_MEMORY_SCOPE_SYSTEM) == g0) {
                __builtin_amdgcn_s_sleep(8);
                if (++polls > (1 << 19)) {
                    __hip_atomic_store(fail, 1, __ATOMIC_RELAXED, __HIP_MEMORY_SCOPE_SYSTEM);
                    break;
                }
            }
            __builtin_amdgcn_fence(__ATOMIC_ACQUIRE, "agent");  // drop stale cached lines (inv L2, once)
        }
    }
    __syncthreads();
}

struct LP {
    const ushort* pk; const ushort* Wq; const ushort* Whh; const ushort* Wpre; const ushort* Wih;
    const float* wE; const int* mask; const float* trg; const float* enc; const ushort* enc_b;
    float* q; float* gh; float* gx; float* e;
    ushort* xcat; ushort* cat2; ushort* h_b; float* h;
    const float* bih; const float* bhh;
    float* d_states; float* out_pre;
    int* bar; int useb;
};

// ---------------------------------------------------------------------------
// Persistent kernel: 512 blocks x 256 threads, 2 blocks/CU co-resident.
// Per step: A(q GEMM) | B(e + gh + pre(t-1)) | C(softmax+ctx) | D(gx) | E(gates)
// with grid barriers between.
// ---------------------------------------------------------------------------
__global__ void __launch_bounds__(256, 2) loop_kernel(LP P)
{
    __shared__ float smem[2592];   // 10368 B: GEMM As/Bs (10240) or sc alpha/wred/part (10256)
    ushort* As = (ushort*)smem;
    ushort* Bs = As + 64 * LDSS;
    const int bid  = blockIdx.x;
    const int tid  = threadIdx.x;
    const int lane = tid & 63;

    for (int t = 0; t < 128; t++) {
        // ---- phase A: q = h @ Wq^T (16 blocks, K-split 2x256) ----
        if (bid < 16) {
            int kc = bid >> 3, nt = bid & 7;
            gemm64x64<false, true>(P.h_b, P.Wq, As, Bs, 512, 512, kc * 256, kc * 256 + 256,
                                   P.q, nullptr, 512, 0, (long)nt * 64);
        }
        gridbar(P.bar);

        // ---- phase B: e (432 blocks) + gh (48 blocks) + pre(t-1) (32 blocks) ----
        if (bid < 432) {
            int wid = (bid << 2) + (tid >> 6);           // 0..1727
            const float* wp = P.wE + lane * 8;
            float4 w0 = *(const float4*)wp, w1 = *(const float4*)(wp + 4);
            int task = wid;                               // task = b*512 + s, < 32768
            bf16x8 pv = *(const bf16x8*)(P.pk + ((long)task << 9) + lane * 8);
            while (1) {
                int nx = task + 1728;
                bool more = nx < 32768;
                bf16x8 pn;
                if (more) pn = *(const bf16x8*)(P.pk + ((long)nx << 9) + lane * 8);
                const float* qp = P.q + ((long)(task >> 9) << 9) + lane * 8;
                float4 q0 = *(const float4*)qp, q1 = *(const float4*)(qp + 4);
                float acc;
                acc  = fast_tanh(q0.x + b2f((ushort)pv[0])) * w0.x;
                acc += fast_tanh(q0.y + b2f((ushort)pv[1])) * w0.y;
                acc += fast_tanh(q0.z + b2f((ushort)pv[2])) * w0.z;
                acc += fast_tanh(q0.w + b2f((ushort)pv[3])) * w0.w;
                acc += fast_tanh(q1.x + b2f((ushort)pv[4])) * w1.x;
                acc += fast_tanh(q1.y + b2f((ushort)pv[5])) * w1.y;
                acc += fast_tanh(q1.z + b2f((ushort)pv[6])) * w1.z;
                acc += fast_tanh(q1.w + b2f((ushort)pv[7])) * w1.w;
#pragma unroll
                for (int off = 32; off; off >>= 1) acc += __shfl_xor(acc, off);
                if (lane == 0) P.e[task] = (P.mask[task] != 0) ? acc : -1e9f;
                if (!more) break;
                pv = pn; task = nx;
            }
        } else if (bid < 480) {
            int b3 = bid - 432, kc = b3 / 24, nt = b3 % 24;
            gemm64x64<false, true>(P.h_b, P.Whh, As, Bs, 512, 512, kc * 256, kc * 256 + 256,
                                   P.gh, nullptr, 1536, 0, (long)nt * 64);
        } else if (t > 0) {
            int b4 = bid - 480, kc = b4 >> 3, nt = b4 & 7;
            gemm64x64<false, true>(P.cat2, P.Wpre, As, Bs, 1792, 1792, kc * 448, kc * 448 + 448,
                                   P.out_pre + (long)(t - 1) * 512, nullptr, 65536, 0, (long)nt * 64);
        }
        gridbar(P.bar);

        // ---- phase C: softmax + context. block -> (b = bid>>3, dc = 2*(bid&7)+{0,1}) ----
        {
            int b   = bid >> 3;
            int dc0 = (bid & 7) << 1;
            float* alpha = smem;            // 512
            float* wred  = smem + 512;      // 4
            float* part  = smem + 516;      // 2048
            float p0 = __expf(P.e[(b << 9) + tid]);        // masked -1e9 -> 0
            float p1 = __expf(P.e[(b << 9) + 256 + tid]);
            alpha[tid] = p0; alpha[tid + 256] = p1;
            float wsum = p0 + p1;
#pragma unroll
            for (int off = 32; off; off >>= 1) wsum += __shfl_xor(wsum, off);
            if (lane == 0) wred[tid >> 6] = wsum;
            __syncthreads();
            float inv = 1.f / (wred[0] + wred[1] + wred[2] + wred[3]);
            if (P.useb) {
                int dg = tid & 7, sp = tid >> 3;
#pragma unroll
                for (int half = 0; half < 2; half++) {
                    int dc = dc0 + half;
                    const ushort* pb = P.enc_b + ((long)b << 19) + (dc << 6) + dg * 8;
                    float a0=0.f,a1=0.f,a2=0.f,a3=0.f,a4=0.f,a5=0.f,a6=0.f,a7=0.f;
                    for (int s = sp; s < 512; s += 32) {
                        bf16x8 v = *(const bf16x8*)(pb + ((long)s << 10));
                        float al = alpha[s];
                        a0 += al * b2f((ushort)v[0]);
                        a1 += al * b2f((ushort)v[1]);
                        a2 += al * b2f((ushort)v[2]);
                        a3 += al * b2f((ushort)v[3]);
                        a4 += al * b2f((ushort)v[4]);
                        a5 += al * b2f((ushort)v[5]);
                        a6 += al * b2f((ushort)v[6]);
                        a7 += al * b2f((ushort)v[7]);
                    }
                    float* pp = part + sp * 64 + dg * 8;
                    pp[0]=a0; pp[1]=a1; pp[2]=a2; pp[3]=a3;
                    pp[4]=a4; pp[5]=a5; pp[6]=a6; pp[7]=a7;
                    __syncthreads();
                    if (tid < 64) {
                        float ctx = 0.f;
#pragma unroll
                        for (int k = 0; k < 32; k++) ctx += part[k * 64 + tid];
                        ctx *= inv;
                        ushort cb = f2b(ctx);
                        int d = (dc << 6) + tid;
                        P.xcat[b * 1280 + 256 + d] = cb;
                        P.cat2[b * 1792 + 768 + d] = cb;
                    } else if (tid >= 128 && tid < 192 && dc < 4) {  // stage x_t (256/b)
                        int dl = tid - 128;
                        ushort xv = f2b(P.trg[((long)b * 128 + t) * 256 + (dc << 6) + dl]);
                        P.xcat[b * 1280 + (dc << 6) + dl] = xv;
                        P.cat2[b * 1792 + (dc << 6) + dl] = xv;
                    }
                    __syncthreads();
                }
            } else {
                int dl = lane, sr = tid >> 6;
#pragma unroll
                for (int half = 0; half < 2; half++) {
                    int dc = dc0 + half;
                    int d = (dc << 6) + dl;
                    const float* pf = P.enc + ((long)b << 19) + d;
                    float a0=0.f,a1=0.f,a2=0.f,a3=0.f;
                    for (int s = sr; s < 512; s += 16) {
                        a0 += alpha[s]      * pf[(long)s << 10];
                        a1 += alpha[s + 4]  * pf[(long)(s + 4) << 10];
                        a2 += alpha[s + 8]  * pf[(long)(s + 8) << 10];
                        a3 += alpha[s + 12] * pf[(long)(s + 12) << 10];
                    }
                    part[tid] = (a0 + a1) + (a2 + a3);
                    __syncthreads();
                    if (sr == 0) {
                        float ctx = (part[dl] + part[64 + dl] + part[128 + dl] + part[192 + dl]) * inv;
                        ushort cb = f2b(ctx);
                        P.xcat[b * 1280 + 256 + d] = cb;
                        P.cat2[b * 1792 + 768 + d] = cb;
                    } else if (sr == 1 && dc < 4) {
                        ushort xv = f2b(P.trg[((long)b * 128 + t) * 256 + (dc << 6) + dl]);
                        P.xcat[b * 1280 + (dc << 6) + dl] = xv;
                        P.cat2[b * 1792 + (dc << 6) + dl] = xv;
                    }
                    __syncthreads();
                }
            }
        }
        gridbar(P.bar);

        // ---- phase D: gx = [x_t, ctx] @ W_ih^T (96 blocks, K-split 4x320) ----
        if (bid < 96) {
            int nt = bid % 24, kc = bid / 24;
            gemm64x64<false, true>(P.xcat, P.Wih, As, Bs, 1280, 1280, kc * 320, kc * 320 + 320,
                                   P.gx, nullptr, 1536, 0, (long)nt * 64);
        }
        gridbar(P.bar);

        // ---- phase E: GRU gates + h update + re-zero accumulators ----
        if (bid < 128) {
            int idx = (bid << 8) + tid;
            int b = idx >> 9, j = idx & 511;
            float* gxp = P.gx + b * 1536;
            float* ghp = P.gh + b * 1536;
            float rx = gxp[j]        + P.bih[j];
            float zx = gxp[j + 512]  + P.bih[j + 512];
            float nx = gxp[j + 1024] + P.bih[j + 1024];
            float rh = ghp[j]        + P.bhh[j];
            float zh = ghp[j + 512]  + P.bhh[j + 512];
            float nh = ghp[j + 1024] + P.bhh[j + 1024];
            float r = 1.f / (1.f + __expf(-(rx + rh)));
            float z = 1.f / (1.f + __expf(-(zx + zh)));
            float n = fast_tanh(nx + r * nh);
            float hn = (1.f - z) * n + z * P.h[idx];
            P.h[idx] = hn;
            P.h_b[idx] = f2b(hn);
            P.cat2[b * 1792 + 256 + j] = f2b(hn);
            P.d_states[((long)b * 128 + t) * 512 + j] = hn;
            gxp[j] = 0.f; gxp[j + 512] = 0.f; gxp[j + 1024] = 0.f;
            ghp[j] = 0.f; ghp[j + 512] = 0.f; ghp[j + 1024] = 0.f;
            P.q[idx] = 0.f;
            P.out_pre[((long)b * 128 + t) * 512 + j] = 0.f;
        }
        gridbar(P.bar);
    }

    // final pre-output GEMM for slice t=127 (cat2 complete after step 127)
    if (bid < 32) {
        int kc = bid >> 3, nt = bid & 7;
        gemm64x64<false, true>(P.cat2, P.Wpre, As, Bs, 1792, 1792, kc * 448, kc * 448 + 448,
                               P.out_pre + (long)127 * 512, nullptr, 65536, 0, (long)nt * 64);
    }
}

// bridge tanh + zero-init all atomic accumulators and the grid barrier.
__global__ void btanh_kernel(const float* __restrict__ br, const float* __restrict__ bbr,
                             float* __restrict__ h, ushort* __restrict__ h_b,
                             float* __restrict__ q, float* __restrict__ gh,
                             float* __restrict__ gx, int* __restrict__ bar)
{
    int idx = blockIdx.x * blockDim.x + threadIdx.x;  // 0..32767
    if (idx < 16) bar[idx] = 0;
    int b = idx >> 9, j = idx & 511;
    float v = fast_tanh(br[idx] + bbr[j]);
    h[idx] = v;
    h_b[idx] = f2b(v);
    q[idx] = 0.f;
    gh[b * 1536 + j] = 0.f; gh[b * 1536 + j + 512] = 0.f; gh[b * 1536 + j + 1024] = 0.f;
    gx[b * 1536 + j] = 0.f; gx[b * 1536 + j + 512] = 0.f; gx[b * 1536 + j + 1024] = 0.f;
}

__global__ void hid_kernel(const float* __restrict__ h, float* __restrict__ out)
{
    int idx = blockIdx.x * blockDim.x + threadIdx.x;
    out[idx] = h[idx];
}

extern "C" void kernel_launch(void* const* d_in, const int* in_sizes, int n_in,
                              void* d_out, int out_size, void* d_ws, size_t ws_size,
                              hipStream_t stream)
{
    (void)in_sizes; (void)n_in; (void)out_size;
    const float* trg  = (const float*)d_in[0];
    const float* enc  = (const float*)d_in[1];
    const float* encF = (const float*)d_in[2];
    const int*   mask = (const int*)d_in[3];
    const float* Wkey = (const float*)d_in[4];
    const float* Wq   = (const float*)d_in[5];
    const float* wE   = (const float*)d_in[6];
    const float* Wbr  = (const float*)d_in[7];
    const float* bbr  = (const float*)d_in[8];
    const float* Wih  = (const float*)d_in[9];
    const float* Whh  = (const float*)d_in[10];
    const float* bih  = (const float*)d_in[11];
    const float* bhh  = (const float*)d_in[12];
    const float* Wpre = (const float*)d_in[13];

    char* p = (char*)d_ws;
    auto alloc = [&](size_t bytes) { void* r = (void*)p; p += (bytes + 255) & ~(size_t)255; return r; };
    ushort* pk     = (ushort*)alloc(16777216ul * 2);
    ushort* Wkey_b = (ushort*)alloc(524288ul * 2);
    ushort* Wq_b   = (ushort*)alloc(262144ul * 2);
    ushort* Wbr_b  = (ushort*)alloc(524288ul * 2);
    ushort* Wih_b  = (ushort*)alloc(1966080ul * 2);
    ushort* Whh_b  = (ushort*)alloc(786432ul * 2);
    ushort* Wpre_b = (ushort*)alloc(917504ul * 2);
    float*  h    = (float*)alloc(32768ul * 4);
    ushort* h_b  = (ushort*)alloc(32768ul * 2);
    float*  br   = (float*)alloc(32768ul * 4);
    float*  q    = (float*)alloc(32768ul * 4);
    float*  gh   = (float*)alloc(98304ul * 4);
    float*  gx   = (float*)alloc(98304ul * 4);
    float*  e    = (float*)alloc(32768ul * 4);
    ushort* xcat = (ushort*)alloc(81920ul * 2);
    ushort* cat2 = (ushort*)alloc(114688ul * 2);
    int*    bar  = (int*)alloc(64ul * 4);
    size_t used = (size_t)(p - (char*)d_ws);
    int useb = (used + 33554432ul * 2 <= ws_size) ? 1 : 0;
    ushort* enc_b = useb ? (ushort*)alloc(33554432ul * 2) : nullptr;

    float* out_states = (float*)d_out;
    float* out_hidden = out_states + 64l * 128 * 512;
    float* out_pre    = out_hidden + 64l * 512;

    f2b4_kernel<<<512, 256, 0, stream>>>((const float4*)Wkey, (ushort4*)Wkey_b, 131072);
    f2b4_kernel<<<256, 256, 0, stream>>>((const float4*)Wq,   (ushort4*)Wq_b,   65536);
    f2b4_kernel<<<512, 256, 0, stream>>>((const float4*)Wbr,  (ushort4*)Wbr_b,  131072);
    f2b4_kernel<<<1920, 256, 0, stream>>>((const float4*)Wih, (ushort4*)Wih_b,  491520);
    f2b4_kernel<<<768, 256, 0, stream>>>((const float4*)Whh,  (ushort4*)Whh_b,  196608);
    f2b4_kernel<<<896, 256, 0, stream>>>((const float4*)Wpre, (ushort4*)Wpre_b, 229376);

    if (useb) {
        f2b4_kernel<<<8192, 256, 0, stream>>>((const float4*)enc, (ushort4*)enc_b, 8388608);
        gemm_nt<false><<<4096, 256, 0, stream>>>(enc_b, Wkey_b, nullptr, pk, 1024, 1024, 512, 1024, 8);
    } else {
        gemm_nt<true><<<4096, 256, 0, stream>>>(enc, Wkey_b, nullptr, pk, 1024, 1024, 512, 1024, 8);
    }
    gemm_nt<true><<<8, 256, 0, stream>>>(encF, Wbr_b, br, nullptr, 1024, 1024, 512, 1024, 8);
    btanh_kernel<<<128, 256, 0, stream>>>(br, bbr, h, h_b, q, gh, gx, bar);

    LP P;
    P.pk = pk; P.Wq = Wq_b; P.Whh = Whh_b; P.Wpre = Wpre_b; P.Wih = Wih_b;
    P.wE = wE; P.mask = mask; P.trg = trg; P.enc = enc; P.enc_b = enc_b;
    P.q = q; P.gh = gh; P.gx = gx; P.e = e;
    P.xcat = xcat; P.cat2 = cat2; P.h_b = h_b; P.h = h;
    P.bih = bih; P.bhh = bhh;
    P.d_states = out_states; P.out_pre = out_pre;
    P.bar = bar; P.useb = useb;
    loop_kernel<<<512, 256, 0, stream>>>(P);

    hid_kernel<<<128, 256, 0, stream>>>(h, out_hidden);
}

// Round 5
// 12024.309 us; speedup vs baseline: 5.2177x; 2.5621x over previous
//
#include <hip/hip_runtime.h>

// DecoderModule: B=64, T=128, S=512, E=256, H=512, 2H=1024, GRU_IN=1280
// Persistent kernel, round 3 (resubmitted: 2x GPU-acquisition timeout, never ran):
// ZERO-FENCE grid barrier.
//  - Inter-phase data (q,e,xcat,cat2,h_b,gx,gh,zero-reinits) uses relaxed
//    AGENT-scope atomics (L2-bypass, coherence-point ops, no cache maint).
//  - Read-only data (pk, enc_b, weights, trg, mask) stays plain-cached and
//    is never invalidated -> L2-resident across all 128 steps.
//  - Barrier: relaxed agent atomics, monotonic counters (no resets), no fences.
//  - h persists in registers across the t-loop (same block owns each (b,j)).

#define LDSS 40  // padded LDS row stride in shorts (80B = 5*16B)

typedef short bf16x8 __attribute__((ext_vector_type(8)));
typedef float f32x4 __attribute__((ext_vector_type(4)));

__device__ inline ushort f2b(float f) {
    unsigned int u = __float_as_uint(f);
    return (ushort)((u + 0x7FFFu + ((u >> 16) & 1u)) >> 16);
}
__device__ inline float b2f(ushort u) {
    return __uint_as_float(((unsigned int)u) << 16);
}
__device__ inline float fast_tanh(float x) {
    x = fminf(fmaxf(x, -15.f), 15.f);
    float ex = __expf(2.f * x);
    return (ex - 1.f) / (ex + 1.f);
}

// coherent (agent-scope, relaxed) accessors: compile to global ops with
// L2-bypass bits; no wb/inv cache maintenance.
__device__ inline uint  cload(const uint* p)  { return __hip_atomic_load(p, __ATOMIC_RELAXED, __HIP_MEMORY_SCOPE_AGENT); }
__device__ inline float cloadf(const float* p){ return __hip_atomic_load(p, __ATOMIC_RELAXED, __HIP_MEMORY_SCOPE_AGENT); }
__device__ inline void  cstore(uint* p, uint v)   { __hip_atomic_store(p, v, __ATOMIC_RELAXED, __HIP_MEMORY_SCOPE_AGENT); }
__device__ inline void  cstoref(float* p, float v){ __hip_atomic_store(p, v, __ATOMIC_RELAXED, __HIP_MEMORY_SCOPE_AGENT); }

__global__ void f2b4_kernel(const float4* __restrict__ in, ushort4* __restrict__ out, int n4) {
    int i = blockIdx.x * blockDim.x + threadIdx.x;
    int stride = gridDim.x * blockDim.x;
    for (; i < n4; i += stride) {
        float4 v = in[i];
        ushort4 o;
        o.x = f2b(v.x); o.y = f2b(v.y); o.z = f2b(v.z); o.w = f2b(v.w);
        out[i] = o;
    }
}

// ---------------------------------------------------------------------------
// 64x64 MFMA bf16 NT-GEMM tile over K range [kbeg,kend).
// ACOH: A-operand loaded via coherent dword loads (for loop-written buffers).
// ---------------------------------------------------------------------------
template <bool AF32, bool ATOMIC, bool ACOH>
__device__ inline void gemm64x64(const void* __restrict__ Av,
                                 const ushort* __restrict__ B,
                                 ushort* As, ushort* Bs,
                                 int lda, int ldb, int kbeg, int kend,
                                 float* Cf, ushort* Cb, long ldc,
                                 long m0, long n0)
{
    const int tid  = threadIdx.x;
    const int wave = tid >> 6;
    const int lane = tid & 63;
    const int row  = tid >> 2;
    const int kcol = (tid & 3) * 8;
    const int lrow = lane & 15;
    const int quad = lane >> 4;

    f32x4 acc[4];
#pragma unroll
    for (int i = 0; i < 4; i++) acc[i] = f32x4{0.f, 0.f, 0.f, 0.f};

    const ushort* Ab  = (const ushort*)Av + (m0 + row) * (long)lda + kcol;
    const float*  Afp = (const float*)Av + (m0 + row) * (long)lda + kcol;
    const ushort* Bp  = B + (n0 + row) * (long)ldb + kcol;
    ushort* AsW = As + row * LDSS + kcol;
    ushort* BsW = Bs + row * LDSS + kcol;
    const ushort* AsR = As + (wave * 16 + lrow) * LDSS + quad * 8;
    const ushort* BsR = Bs + lrow * LDSS + quad * 8;

    for (int k0 = kbeg; k0 < kend; k0 += 32) {
        uint4 av;
        if (AF32) {
            float4 f0 = *(const float4*)(Afp + k0);
            float4 f1 = *(const float4*)(Afp + k0 + 4);
            av.x = (uint)f2b(f0.x) | ((uint)f2b(f0.y) << 16);
            av.y = (uint)f2b(f0.z) | ((uint)f2b(f0.w) << 16);
            av.z = (uint)f2b(f1.x) | ((uint)f2b(f1.y) << 16);
            av.w = (uint)f2b(f1.z) | ((uint)f2b(f1.w) << 16);
        } else if (ACOH) {
            const uint* up = (const uint*)(Ab + k0);
            av.x = cload(up); av.y = cload(up + 1); av.z = cload(up + 2); av.w = cload(up + 3);
        } else {
            av = *(const uint4*)(Ab + k0);
        }
        uint4 bv = *(const uint4*)(Bp + k0);
        __syncthreads();
        *(uint4*)AsW = av;
        *(uint4*)BsW = bv;
        __syncthreads();
        bf16x8 af = *(const bf16x8*)AsR;
#pragma unroll
        for (int nf = 0; nf < 4; nf++) {
            bf16x8 bfv = *(const bf16x8*)(BsR + nf * 16 * LDSS);
            acc[nf] = __builtin_amdgcn_mfma_f32_16x16x32_bf16(af, bfv, acc[nf], 0, 0, 0);
        }
    }

#pragma unroll
    for (int nf = 0; nf < 4; nf++) {
#pragma unroll
        for (int r = 0; r < 4; r++) {
            long m = m0 + wave * 16 + quad * 4 + r;
            long n = n0 + nf * 16 + lrow;
            float v = acc[nf][r];
            if (ATOMIC)      atomicAdd(&Cf[m * ldc + n], v);
            else if (Cf)     Cf[m * ldc + n] = v;
            else             Cb[m * ldc + n] = f2b(v);
        }
    }
}

template <bool AF32>
__global__ void gemm_nt(const void* __restrict__ A, const ushort* __restrict__ B,
                        float* Cf, ushort* Cb,
                        int lda, int ldb, long ldc, int K, int nTilesN)
{
    __shared__ ushort As[64 * LDSS];
    __shared__ ushort Bs[64 * LDSS];
    long m0 = (long)(blockIdx.x / nTilesN) * 64;
    long n0 = (long)(blockIdx.x % nTilesN) * 64;
    gemm64x64<AF32, false, false>(A, B, As, Bs, lda, ldb, 0, K, Cf, Cb, ldc, m0, n0);
}

// ---------------------------------------------------------------------------
// Zero-fence two-level grid barrier. Monotonic counters (no resets -> no
// reset/arrival reorder race). bar[0..7]=group counters, bar[8]=groups-done,
// bar[32]=generation, bar[48]=fail flag. All relaxed agent-scope.
// Visibility: __syncthreads' vmcnt(0) drain completes prior coherent stores
// at the coherence point before tid0 arrives.
// ---------------------------------------------------------------------------
__device__ inline void gridbar(int* bar) {
    __syncthreads();
    if (threadIdx.x == 0) {
        int* gen  = bar + 32;
        int* fail = bar + 48;
        if (__hip_atomic_load(fail, __ATOMIC_RELAXED, __HIP_MEMORY_SCOPE_AGENT) == 0) {
            int g0 = __hip_atomic_load(gen, __ATOMIC_RELAXED, __HIP_MEMORY_SCOPE_AGENT);
            int grp = blockIdx.x & 7;
            int my = __hip_atomic_fetch_add(bar + grp, 1, __ATOMIC_RELAXED, __HIP_MEMORY_SCOPE_AGENT);
            if ((my & 63) == 63) {
                int md = __hip_atomic_fetch_add(bar + 8, 1, __ATOMIC_RELAXED, __HIP_MEMORY_SCOPE_AGENT);
                if ((md & 7) == 7) {
                    __hip_atomic_fetch_add(gen, 1, __ATOMIC_RELAXED, __HIP_MEMORY_SCOPE_AGENT);
                }
            }
            int polls = 0;
            while (__hip_atomic_load(gen, __ATOMIC_RELAXED, __HIP_MEMORY_SCOPE_AGENT) == g0) {
                __builtin_amdgcn_s_sleep(8);
                if (++polls > (1 << 20)) {
                    __hip_atomic_store(fail, 1, __ATOMIC_RELAXED, __HIP_MEMORY_SCOPE_AGENT);
                    break;
                }
            }
        }
    }
    __syncthreads();
}

struct LP {
    const ushort* pk; const ushort* Wq; const ushort* Whh; const ushort* Wpre; const ushort* Wih;
    const float* wE; const int* mask; const float* trg; const float* enc; const ushort* enc_b;
    float* q; float* gh; float* gx; float* e;
    ushort* xcat; ushort* cat2; ushort* h_b; float* h;
    const float* bih; const float* bhh;
    float* d_states; float* out_pre; float* out_hidden;
    int* bar; int useb;
};

// ---------------------------------------------------------------------------
// Persistent kernel: 512 blocks x 256 threads, 2 blocks/CU.
// Per step: A(q GEMM) | B(e + gh + pre(t-1)) | C(softmax+ctx) | D(gx) | E(gates)
// ---------------------------------------------------------------------------
__global__ void __launch_bounds__(256, 2) loop_kernel(LP P)
{
    __shared__ float smem[2592];
    ushort* As = (ushort*)smem;
    ushort* Bs = As + 64 * LDSS;
    const int bid  = blockIdx.x;
    const int tid  = threadIdx.x;
    const int lane = tid & 63;

    // h lives in a register: block bid<128 owns (b = idx>>9, j = idx&511).
    const int idx = (bid << 8) + tid;
    float hreg = 0.f;
    if (bid < 128) hreg = P.h[idx];   // written by btanh (kernel-boundary coherent)

    for (int t = 0; t < 128; t++) {
        // ---- phase A: q = h @ Wq^T (16 blocks, K-split 2x256) ----
        if (bid < 16) {
            int kc = bid >> 3, nt = bid & 7;
            gemm64x64<false, true, true>(P.h_b, P.Wq, As, Bs, 512, 512, kc * 256, kc * 256 + 256,
                                         P.q, nullptr, 512, 0, (long)nt * 64);
        }
        gridbar(P.bar);

        // ---- phase B: e (256 blocks) + gh (48) + pre(t-1) (32) ----
        if (bid < 256) {
            // block handles b = bid>>2, s-range of 128; q[b] staged to LDS once.
            int b = bid >> 2;
            float* qlds = smem;
            qlds[tid]       = cloadf(P.q + b * 512 + tid);
            qlds[tid + 256] = cloadf(P.q + b * 512 + 256 + tid);
            __syncthreads();
            const float* wp = P.wE + lane * 8;
            float4 w0 = *(const float4*)wp, w1 = *(const float4*)(wp + 4);
            const float* qp = qlds + lane * 8;
            float4 q0 = *(const float4*)qp, q1 = *(const float4*)(qp + 4);
            int s0 = ((bid & 3) << 7) + ((tid >> 6) << 5);   // 32 s per wave
            const ushort* pkb = P.pk + ((long)b << 18) + lane * 8;
            bf16x8 pv = *(const bf16x8*)(pkb + ((long)s0 << 9));
            for (int j = 0; j < 32; j++) {
                int s = s0 + j;
                bf16x8 pn;
                if (j < 31) pn = *(const bf16x8*)(pkb + ((long)(s + 1) << 9));
                float acc;
                acc  = fast_tanh(q0.x + b2f((ushort)pv[0])) * w0.x;
                acc += fast_tanh(q0.y + b2f((ushort)pv[1])) * w0.y;
                acc += fast_tanh(q0.z + b2f((ushort)pv[2])) * w0.z;
                acc += fast_tanh(q0.w + b2f((ushort)pv[3])) * w0.w;
                acc += fast_tanh(q1.x + b2f((ushort)pv[4])) * w1.x;
                acc += fast_tanh(q1.y + b2f((ushort)pv[5])) * w1.y;
                acc += fast_tanh(q1.z + b2f((ushort)pv[6])) * w1.z;
                acc += fast_tanh(q1.w + b2f((ushort)pv[7])) * w1.w;
#pragma unroll
                for (int off = 32; off; off >>= 1) acc += __shfl_xor(acc, off);
                if (lane == 0) {
                    int i = (b << 9) + s;
                    cstoref(P.e + i, (P.mask[i] != 0) ? acc : -1e9f);
                }
                pv = pn;
            }
        } else if (bid < 304) {
            int b3 = bid - 256, kc = b3 / 24, nt = b3 % 24;
            gemm64x64<false, true, true>(P.h_b, P.Whh, As, Bs, 512, 512, kc * 256, kc * 256 + 256,
                                         P.gh, nullptr, 1536, 0, (long)nt * 64);
        } else if (bid < 336 && t > 0) {
            int b4 = bid - 304, kc = b4 >> 3, nt = b4 & 7;
            gemm64x64<false, true, true>(P.cat2, P.Wpre, As, Bs, 1792, 1792, kc * 448, kc * 448 + 448,
                                         P.out_pre + (long)(t - 1) * 512, nullptr, 65536, 0, (long)nt * 64);
        }
        gridbar(P.bar);

        // ---- phase C: softmax + context. block -> (b = bid>>3, dc = 2*(bid&7)+{0,1}) ----
        {
            int b   = bid >> 3;
            int dc0 = (bid & 7) << 1;
            float* alpha = smem;            // 512
            float* wred  = smem + 512;      // 4
            float* part  = smem + 516;      // 2048
            float p0 = __expf(cloadf(P.e + (b << 9) + tid));
            float p1 = __expf(cloadf(P.e + (b << 9) + 256 + tid));
            alpha[tid] = p0; alpha[tid + 256] = p1;
            float wsum = p0 + p1;
#pragma unroll
            for (int off = 32; off; off >>= 1) wsum += __shfl_xor(wsum, off);
            if (lane == 0) wred[tid >> 6] = wsum;
            __syncthreads();
            float inv = 1.f / (wred[0] + wred[1] + wred[2] + wred[3]);
            if (P.useb) {
                int dg = tid & 7, sp = tid >> 3;
#pragma unroll
                for (int half = 0; half < 2; half++) {
                    int dc = dc0 + half;
                    const ushort* pb = P.enc_b + ((long)b << 19) + (dc << 6) + dg * 8;
                    float a0=0.f,a1=0.f,a2=0.f,a3=0.f,a4=0.f,a5=0.f,a6=0.f,a7=0.f;
                    for (int s = sp; s < 512; s += 32) {
                        bf16x8 v = *(const bf16x8*)(pb + ((long)s << 10));
                        float al = alpha[s];
                        a0 += al * b2f((ushort)v[0]);
                        a1 += al * b2f((ushort)v[1]);
                        a2 += al * b2f((ushort)v[2]);
                        a3 += al * b2f((ushort)v[3]);
                        a4 += al * b2f((ushort)v[4]);
                        a5 += al * b2f((ushort)v[5]);
                        a6 += al * b2f((ushort)v[6]);
                        a7 += al * b2f((ushort)v[7]);
                    }
                    float* pp = part + sp * 64 + dg * 8;
                    pp[0]=a0; pp[1]=a1; pp[2]=a2; pp[3]=a3;
                    pp[4]=a4; pp[5]=a5; pp[6]=a6; pp[7]=a7;
                    __syncthreads();
                    if (tid < 64) {   // wave 0: ctx, pair-packed coherent stores
                        float ctx = 0.f;
#pragma unroll
                        for (int k = 0; k < 32; k++) ctx += part[k * 64 + tid];
                        ctx *= inv;
                        uint cb = (uint)f2b(ctx);
                        uint prt = __shfl_xor(cb, 1);
                        if (!(lane & 1)) {
                            uint w = cb | (prt << 16);
                            cstore((uint*)(P.xcat + b * 1280 + 256 + (dc << 6)) + (lane >> 1), w);
                            cstore((uint*)(P.cat2 + b * 1792 + 768 + (dc << 6)) + (lane >> 1), w);
                        }
                    } else if (tid >= 128 && tid < 192) {  // wave 2: stage x_t
                        if (dc < 4) {
                            int dl = tid - 128;
                            uint xv = (uint)f2b(P.trg[((long)b * 128 + t) * 256 + (dc << 6) + dl]);
                            uint prt = __shfl_xor(xv, 1);
                            if (!(dl & 1)) {
                                uint w = xv | (prt << 16);
                                cstore((uint*)(P.xcat + b * 1280 + (dc << 6)) + (dl >> 1), w);
                                cstore((uint*)(P.cat2 + b * 1792 + (dc << 6)) + (dl >> 1), w);
                            }
                        }
                    }
                    __syncthreads();
                }
            } else {
                int dl = lane, sr = tid >> 6;
#pragma unroll
                for (int half = 0; half < 2; half++) {
                    int dc = dc0 + half;
                    int d = (dc << 6) + dl;
                    const float* pf = P.enc + ((long)b << 19) + d;
                    float a0=0.f,a1=0.f,a2=0.f,a3=0.f;
                    for (int s = sr; s < 512; s += 16) {
                        a0 += alpha[s]      * pf[(long)s << 10];
                        a1 += alpha[s + 4]  * pf[(long)(s + 4) << 10];
                        a2 += alpha[s + 8]  * pf[(long)(s + 8) << 10];
                        a3 += alpha[s + 12] * pf[(long)(s + 12) << 10];
                    }
                    part[tid] = (a0 + a1) + (a2 + a3);
                    __syncthreads();
                    if (sr == 0) {
                        float ctx = (part[dl] + part[64 + dl] + part[128 + dl] + part[192 + dl]) * inv;
                        uint cb = (uint)f2b(ctx);
                        uint prt = __shfl_xor(cb, 1);
                        if (!(dl & 1)) {
                            uint w = cb | (prt << 16);
                            cstore((uint*)(P.xcat + b * 1280 + 256 + (dc << 6)) + (dl >> 1), w);
                            cstore((uint*)(P.cat2 + b * 1792 + 768 + (dc << 6)) + (dl >> 1), w);
                        }
                    } else if (sr == 1) {
                        if (dc < 4) {
                            uint xv = (uint)f2b(P.trg[((long)b * 128 + t) * 256 + (dc << 6) + dl]);
                            uint prt = __shfl_xor(xv, 1);
                            if (!(dl & 1)) {
                                uint w = xv | (prt << 16);
                                cstore((uint*)(P.xcat + b * 1280 + (dc << 6)) + (dl >> 1), w);
                                cstore((uint*)(P.cat2 + b * 1792 + (dc << 6)) + (dl >> 1), w);
                            }
                        }
                    }
                    __syncthreads();
                }
            }
        }
        gridbar(P.bar);

        // ---- phase D: gx = [x_t, ctx] @ W_ih^T (96 blocks, K-split 4x320) ----
        if (bid < 96) {
            int nt = bid % 24, kc = bid / 24;
            gemm64x64<false, true, true>(P.xcat, P.Wih, As, Bs, 1280, 1280, kc * 320, kc * 320 + 320,
                                         P.gx, nullptr, 1536, 0, (long)nt * 64);
        }
        gridbar(P.bar);

        // ---- phase E: GRU gates + h update + re-zero accumulators ----
        if (bid < 128) {
            int b = idx >> 9, j = idx & 511;
            float* gxp = P.gx + b * 1536;
            float* ghp = P.gh + b * 1536;
            float rx = cloadf(gxp + j)        + P.bih[j];
            float zx = cloadf(gxp + j + 512)  + P.bih[j + 512];
            float nx = cloadf(gxp + j + 1024) + P.bih[j + 1024];
            float rh = cloadf(ghp + j)        + P.bhh[j];
            float zh = cloadf(ghp + j + 512)  + P.bhh[j + 512];
            float nh = cloadf(ghp + j + 1024) + P.bhh[j + 1024];
            float r = 1.f / (1.f + __expf(-(rx + rh)));
            float z = 1.f / (1.f + __expf(-(zx + zh)));
            float n = fast_tanh(nx + r * nh);
            float hn = (1.f - z) * n + z * hreg;
            hreg = hn;
            uint hb = (uint)f2b(hn);
            uint prt = __shfl_xor(hb, 1);
            if (!(lane & 1)) {
                uint w = hb | (prt << 16);
                cstore((uint*)(P.h_b + (idx & ~1)), w);
                cstore((uint*)(P.cat2 + b * 1792 + 256 + (j & ~1)), w);
            }
            P.d_states[((long)b * 128 + t) * 512 + j] = hn;   // pure output
            cstoref(gxp + j, 0.f); cstoref(gxp + j + 512, 0.f); cstoref(gxp + j + 1024, 0.f);
            cstoref(ghp + j, 0.f); cstoref(ghp + j + 512, 0.f); cstoref(ghp + j + 1024, 0.f);
            cstoref(P.q + idx, 0.f);
            cstoref(P.out_pre + ((long)b * 128 + t) * 512 + j, 0.f);
        }
        gridbar(P.bar);
    }

    // final pre-output GEMM for slice t=127 + hidden output
    if (bid < 32) {
        int kc = bid >> 3, nt = bid & 7;
        gemm64x64<false, true, true>(P.cat2, P.Wpre, As, Bs, 1792, 1792, kc * 448, kc * 448 + 448,
                                     P.out_pre + (long)127 * 512, nullptr, 65536, 0, (long)nt * 64);
    }
    if (bid < 128) P.out_hidden[idx] = hreg;
}

// bridge tanh + zero-init accumulators and barrier state.
__global__ void btanh_kernel(const float* __restrict__ br, const float* __restrict__ bbr,
                             float* __restrict__ h, ushort* __restrict__ h_b,
                             float* __restrict__ q, float* __restrict__ gh,
                             float* __restrict__ gx, int* __restrict__ bar)
{
    int idx = blockIdx.x * blockDim.x + threadIdx.x;  // 0..32767
    if (idx < 64) bar[idx] = 0;
    int b = idx >> 9, j = idx & 511;
    float v = fast_tanh(br[idx] + bbr[j]);
    h[idx] = v;
    h_b[idx] = f2b(v);
    q[idx] = 0.f;
    gh[b * 1536 + j] = 0.f; gh[b * 1536 + j + 512] = 0.f; gh[b * 1536 + j + 1024] = 0.f;
    gx[b * 1536 + j] = 0.f; gx[b * 1536 + j + 512] = 0.f; gx[b * 1536 + j + 1024] = 0.f;
}

extern "C" void kernel_launch(void* const* d_in, const int* in_sizes, int n_in,
                              void* d_out, int out_size, void* d_ws, size_t ws_size,
                              hipStream_t stream)
{
    (void)in_sizes; (void)n_in; (void)out_size;
    const float* trg  = (const float*)d_in[0];
    const float* enc  = (const float*)d_in[1];
    const float* encF = (const float*)d_in[2];
    const int*   mask = (const int*)d_in[3];
    const float* Wkey = (const float*)d_in[4];
    const float* Wq   = (const float*)d_in[5];
    const float* wE   = (const float*)d_in[6];
    const float* Wbr  = (const float*)d_in[7];
    const float* bbr  = (const float*)d_in[8];
    const float* Wih  = (const float*)d_in[9];
    const float* Whh  = (const float*)d_in[10];
    const float* bih  = (const float*)d_in[11];
    const float* bhh  = (const float*)d_in[12];
    const float* Wpre = (const float*)d_in[13];

    char* p = (char*)d_ws;
    auto alloc = [&](size_t bytes) { void* r = (void*)p; p += (bytes + 255) & ~(size_t)255; return r; };
    ushort* pk     = (ushort*)alloc(16777216ul * 2);
    ushort* Wkey_b = (ushort*)alloc(524288ul * 2);
    ushort* Wq_b   = (ushort*)alloc(262144ul * 2);
    ushort* Wbr_b  = (ushort*)alloc(524288ul * 2);
    ushort* Wih_b  = (ushort*)alloc(1966080ul * 2);
    ushort* Whh_b  = (ushort*)alloc(786432ul * 2);
    ushort* Wpre_b = (ushort*)alloc(917504ul * 2);
    float*  h    = (float*)alloc(32768ul * 4);
    ushort* h_b  = (ushort*)alloc(32768ul * 2);
    float*  br   = (float*)alloc(32768ul * 4);
    float*  q    = (float*)alloc(32768ul * 4);
    float*  gh   = (float*)alloc(98304ul * 4);
    float*  gx   = (float*)alloc(98304ul * 4);
    float*  e    = (float*)alloc(32768ul * 4);
    ushort* xcat = (ushort*)alloc(81920ul * 2);
    ushort* cat2 = (ushort*)alloc(114688ul * 2);
    int*    bar  = (int*)alloc(64ul * 4);
    size_t used = (size_t)(p - (char*)d_ws);
    int useb = (used + 33554432ul * 2 <= ws_size) ? 1 : 0;
    ushort* enc_b = useb ? (ushort*)alloc(33554432ul * 2) : nullptr;

    float* out_states = (float*)d_out;
    float* out_hidden = out_states + 64l * 128 * 512;
    float* out_pre    = out_hidden + 64l * 512;

    f2b4_kernel<<<512, 256, 0, stream>>>((const float4*)Wkey, (ushort4*)Wkey_b, 131072);
    f2b4_kernel<<<256, 256, 0, stream>>>((const float4*)Wq,   (ushort4*)Wq_b,   65536);
    f2b4_kernel<<<512, 256, 0, stream>>>((const float4*)Wbr,  (ushort4*)Wbr_b,  131072);
    f2b4_kernel<<<1920, 256, 0, stream>>>((const float4*)Wih, (ushort4*)Wih_b,  491520);
    f2b4_kernel<<<768, 256, 0, stream>>>((const float4*)Whh,  (ushort4*)Whh_b,  196608);
    f2b4_kernel<<<896, 256, 0, stream>>>((const float4*)Wpre, (ushort4*)Wpre_b, 229376);

    if (useb) {
        f2b4_kernel<<<8192, 256, 0, stream>>>((const float4*)enc, (ushort4*)enc_b, 8388608);
        gemm_nt<false><<<4096, 256, 0, stream>>>(enc_b, Wkey_b, nullptr, pk, 1024, 1024, 512, 1024, 8);
    } else {
        gemm_nt<true><<<4096, 256, 0, stream>>>(enc, Wkey_b, nullptr, pk, 1024, 1024, 512, 1024, 8);
    }
    gemm_nt<true><<<8, 256, 0, stream>>>(encF, Wbr_b, br, nullptr, 1024, 1024, 512, 1024, 8);
    btanh_kernel<<<128, 256, 0, stream>>>(br, bbr, h, h_b, q, gh, gx, bar);

    LP P;
    P.pk = pk; P.Wq = Wq_b; P.Whh = Whh_b; P.Wpre = Wpre_b; P.Wih = Wih_b;
    P.wE = wE; P.mask = mask; P.trg = trg; P.enc = enc; P.enc_b = enc_b;
    P.q = q; P.gh = gh; P.gx = gx; P.e = e;
    P.xcat = xcat; P.cat2 = cat2; P.h_b = h_b; P.h = h;
    P.bih = bih; P.bhh = bhh;
    P.d_states = out_states; P.out_pre = out_pre; P.out_hidden = out_hidden;
    P.bar = bar; P.useb = useb;
    loop_kernel<<<512, 256, 0, stream>>>(P);
}

// Round 10
// 9400.346 us; speedup vs baseline: 6.6741x; 1.2791x over previous
//
#include <hip/hip_runtime.h>

// DecoderModule: B=64, T=128, S=512, E=256, H=512, 2H=1024, GRU_IN=1280
// Persistent kernel round 6 (5th submit; all prior attempts hit
// GPU-acquisition timeouts, never executed): 1024 blocks (4/CU), transposed
// enc_t[b][d][s] for coalesced context reduction, rebalanced phases,
// per-group gen lines.

#define LDSS 40  // padded LDS row stride in shorts (80B = 5*16B)

typedef short bf16x8 __attribute__((ext_vector_type(8)));
typedef float f32x4 __attribute__((ext_vector_type(4)));

__device__ inline ushort f2b(float f) {
    unsigned int u = __float_as_uint(f);
    return (ushort)((u + 0x7FFFu + ((u >> 16) & 1u)) >> 16);
}
__device__ inline float b2f(ushort u) {
    return __uint_as_float(((unsigned int)u) << 16);
}
__device__ inline float fast_tanh(float x) {
    x = fminf(fmaxf(x, -15.f), 15.f);
    float ex = __expf(2.f * x);
    return (ex - 1.f) / (ex + 1.f);
}

// coherent (agent-scope, relaxed) accessors
__device__ inline uint  cload(const uint* p)  { return __hip_atomic_load(p, __ATOMIC_RELAXED, __HIP_MEMORY_SCOPE_AGENT); }
__device__ inline float cloadf(const float* p){ return __hip_atomic_load(p, __ATOMIC_RELAXED, __HIP_MEMORY_SCOPE_AGENT); }
__device__ inline void  cstore(uint* p, uint v)    { __hip_atomic_store(p, v, __ATOMIC_RELAXED, __HIP_MEMORY_SCOPE_AGENT); }
__device__ inline void  cstoref(float* p, float v) { __hip_atomic_store(p, v, __ATOMIC_RELAXED, __HIP_MEMORY_SCOPE_AGENT); }
__device__ inline void  cstoreu(ushort* p, ushort v){ __hip_atomic_store(p, v, __ATOMIC_RELAXED, __HIP_MEMORY_SCOPE_AGENT); }

__global__ void f2b4_kernel(const float4* __restrict__ in, ushort4* __restrict__ out, int n4) {
    int i = blockIdx.x * blockDim.x + threadIdx.x;
    int stride = gridDim.x * blockDim.x;
    for (; i < n4; i += stride) {
        float4 v = in[i];
        ushort4 o;
        o.x = f2b(v.x); o.y = f2b(v.y); o.z = f2b(v.z); o.w = f2b(v.w);
        out[i] = o;
    }
}

// enc [b][s][1024d] fp32 -> enc_t [b][d][512s] bf16, 64x64 LDS tile transpose.
__global__ void tr_kernel(const float* __restrict__ enc, ushort* __restrict__ et)
{
    __shared__ ushort lds[64][68];
    int bid = blockIdx.x;                 // 64b * 16dt * 8st = 8192
    int b  = bid >> 7;
    int dt = (bid >> 3) & 15;
    int st = bid & 7;
    int tid = threadIdx.x;
    long base = ((long)b * 512 + st * 64) * 1024 + dt * 64;
#pragma unroll
    for (int i = 0; i < 16; i++) {
        int s = (tid >> 6) + (i << 2);
        int d = tid & 63;
        lds[d][s] = f2b(enc[base + (long)s * 1024 + d]);
    }
    __syncthreads();
    long obase = ((long)b * 1024 + dt * 64) * 512 + st * 64;
#pragma unroll
    for (int i = 0; i < 16; i++) {
        int d = (tid >> 6) + (i << 2);
        int s = tid & 63;
        et[obase + (long)d * 512 + s] = lds[d][s];
    }
}

// ---------------------------------------------------------------------------
// 64x64 MFMA bf16 NT-GEMM tile over K range [kbeg,kend).
// ---------------------------------------------------------------------------
template <bool AF32, bool ATOMIC, bool ACOH>
__device__ inline void gemm64x64(const void* __restrict__ Av,
                                 const ushort* __restrict__ B,
                                 ushort* As, ushort* Bs,
                                 int lda, int ldb, int kbeg, int kend,
                                 float* Cf, ushort* Cb, long ldc,
                                 long m0, long n0)
{
    const int tid  = threadIdx.x;
    const int wave = tid >> 6;
    const int lane = tid & 63;
    const int row  = tid >> 2;
    const int kcol = (tid & 3) * 8;
    const int lrow = lane & 15;
    const int quad = lane >> 4;

    f32x4 acc[4];
#pragma unroll
    for (int i = 0; i < 4; i++) acc[i] = f32x4{0.f, 0.f, 0.f, 0.f};

    const ushort* Ab  = (const ushort*)Av + (m0 + row) * (long)lda + kcol;
    const float*  Afp = (const float*)Av + (m0 + row) * (long)lda + kcol;
    const ushort* Bp  = B + (n0 + row) * (long)ldb + kcol;
    ushort* AsW = As + row * LDSS + kcol;
    ushort* BsW = Bs + row * LDSS + kcol;
    const ushort* AsR = As + (wave * 16 + lrow) * LDSS + quad * 8;
    const ushort* BsR = Bs + lrow * LDSS + quad * 8;

    for (int k0 = kbeg; k0 < kend; k0 += 32) {
        uint4 av;
        if (AF32) {
            float4 f0 = *(const float4*)(Afp + k0);
            float4 f1 = *(const float4*)(Afp + k0 + 4);
            av.x = (uint)f2b(f0.x) | ((uint)f2b(f0.y) << 16);
            av.y = (uint)f2b(f0.z) | ((uint)f2b(f0.w) << 16);
            av.z = (uint)f2b(f1.x) | ((uint)f2b(f1.y) << 16);
            av.w = (uint)f2b(f1.z) | ((uint)f2b(f1.w) << 16);
        } else if (ACOH) {
            const uint* up = (const uint*)(Ab + k0);
            av.x = cload(up); av.y = cload(up + 1); av.z = cload(up + 2); av.w = cload(up + 3);
        } else {
            av = *(const uint4*)(Ab + k0);
        }
        uint4 bv = *(const uint4*)(Bp + k0);
        __syncthreads();
        *(uint4*)AsW = av;
        *(uint4*)BsW = bv;
        __syncthreads();
        bf16x8 af = *(const bf16x8*)AsR;
#pragma unroll
        for (int nf = 0; nf < 4; nf++) {
            bf16x8 bfv = *(const bf16x8*)(BsR + nf * 16 * LDSS);
            acc[nf] = __builtin_amdgcn_mfma_f32_16x16x32_bf16(af, bfv, acc[nf], 0, 0, 0);
        }
    }

#pragma unroll
    for (int nf = 0; nf < 4; nf++) {
#pragma unroll
        for (int r = 0; r < 4; r++) {
            long m = m0 + wave * 16 + quad * 4 + r;
            long n = n0 + nf * 16 + lrow;
            float v = acc[nf][r];
            if (ATOMIC)      atomicAdd(&Cf[m * ldc + n], v);
            else if (Cf)     Cf[m * ldc + n] = v;
            else             Cb[m * ldc + n] = f2b(v);
        }
    }
}

template <bool AF32>
__global__ void gemm_nt(const void* __restrict__ A, const ushort* __restrict__ B,
                        float* Cf, ushort* Cb,
                        int lda, int ldb, long ldc, int K, int nTilesN)
{
    __shared__ ushort As[64 * LDSS];
    __shared__ ushort Bs[64 * LDSS];
    long m0 = (long)(blockIdx.x / nTilesN) * 64;
    long n0 = (long)(blockIdx.x % nTilesN) * 64;
    gemm64x64<AF32, false, false>(A, B, As, Bs, lda, ldb, 0, K, Cf, Cb, ldc, m0, n0);
}

// ---------------------------------------------------------------------------
// Zero-fence grid barrier for 1024 blocks: 8 groups x 128.
// Layout (ints): arr[g]=bar[g*32], master=bar[256], gen[g]=bar[288+g*32],
// fail=bar[544]. Monotonic counters, relaxed agent atomics, no fences.
// Per-group gen lines -> only 128 pollers per cache line.
// ---------------------------------------------------------------------------
__device__ inline void gridbar(int* bar) {
    __syncthreads();
    if (threadIdx.x == 0) {
        int grp  = blockIdx.x & 7;
        int* arr  = bar + grp * 32;
        int* mst  = bar + 256;
        int* gen  = bar + 288 + grp * 32;
        int* fail = bar + 544;
        if (__hip_atomic_load(fail, __ATOMIC_RELAXED, __HIP_MEMORY_SCOPE_AGENT) == 0) {
            int g0 = __hip_atomic_load(gen, __ATOMIC_RELAXED, __HIP_MEMORY_SCOPE_AGENT);
            int my = __hip_atomic_fetch_add(arr, 1, __ATOMIC_RELAXED, __HIP_MEMORY_SCOPE_AGENT);
            if ((my & 127) == 127) {
                int md = __hip_atomic_fetch_add(mst, 1, __ATOMIC_RELAXED, __HIP_MEMORY_SCOPE_AGENT);
                if ((md & 7) == 7) {
#pragma unroll
                    for (int g = 0; g < 8; g++)
                        __hip_atomic_fetch_add(bar + 288 + g * 32, 1, __ATOMIC_RELAXED, __HIP_MEMORY_SCOPE_AGENT);
                }
            }
            int polls = 0;
            while (__hip_atomic_load(gen, __ATOMIC_RELAXED, __HIP_MEMORY_SCOPE_AGENT) == g0) {
                __builtin_amdgcn_s_sleep(4);
                if (++polls > (1 << 20)) {
                    __hip_atomic_store(fail, 1, __ATOMIC_RELAXED, __HIP_MEMORY_SCOPE_AGENT);
                    break;
                }
            }
        }
    }
    __syncthreads();
}

struct LP {
    const ushort* pk; const ushort* Wq; const ushort* Whh; const ushort* Wpre; const ushort* Wih;
    const float* wE; const int* mask; const float* trg; const float* enc; const ushort* enc_t;
    float* q; float* gh; float* gx; float* e;
    ushort* xcat; ushort* cat2; ushort* h_b; float* h;
    const float* bih; const float* bhh;
    float* d_states; float* out_pre; float* out_hidden;
    int* bar; int useb;
};

// ---------------------------------------------------------------------------
// Persistent kernel: 1024 blocks x 256 threads, 4 blocks/CU.
// Phases: A{q + pre(t-1)} | B{e + gh} | C{softmax+ctx} | D{gx} | E{gates}
// ---------------------------------------------------------------------------
__global__ void __launch_bounds__(256, 4) loop_kernel(LP P)
{
    __shared__ float smem[2592];
    ushort* As = (ushort*)smem;
    ushort* Bs = As + 64 * LDSS;
    const int bid  = blockIdx.x;
    const int tid  = threadIdx.x;
    const int lane = tid & 63;

    // h lives in a register: block bid<128 owns (b = idx>>9, j = idx&511).
    const int idx = (bid << 8) + tid;
    float hreg = 0.f;
    if (bid < 128) hreg = P.h[idx];

    for (int t = 0; t < 128; t++) {
        // ---- phase A: q (32 blocks, K-split 4x128) + pre(t-1) (64 blocks, 8x224) ----
        if (bid < 32) {
            int kc = bid >> 3, nt = bid & 7;
            gemm64x64<false, true, true>(P.h_b, P.Wq, As, Bs, 512, 512, kc * 128, kc * 128 + 128,
                                         P.q, nullptr, 512, 0, (long)nt * 64);
        } else if (bid < 96 && t > 0) {
            int b4 = bid - 32, kc = b4 >> 3, nt = b4 & 7;
            gemm64x64<false, true, true>(P.cat2, P.Wpre, As, Bs, 1792, 1792, kc * 224, kc * 224 + 224,
                                         P.out_pre + (long)(t - 1) * 512, nullptr, 65536, 0, (long)nt * 64);
        }
        gridbar(P.bar);

        // ---- phase B: e (896 blocks, 14/b) + gh (96 blocks, 4x128) ----
        if (bid < 896) {
            int b = bid / 14, sub = bid - b * 14;
            float* qlds = smem;
            qlds[tid]       = cloadf(P.q + b * 512 + tid);
            qlds[tid + 256] = cloadf(P.q + b * 512 + 256 + tid);
            __syncthreads();
            const float* wp = P.wE + lane * 8;
            float4 w0 = *(const float4*)wp, w1 = *(const float4*)(wp + 4);
            const float* qp = qlds + lane * 8;
            float4 q0 = *(const float4*)qp, q1 = *(const float4*)(qp + 4);
            int ws = (sub << 2) + (tid >> 6);           // 0..55
            const ushort* pkb = P.pk + ((long)b << 18) + lane * 8;
            int s = ws;
            bf16x8 pv = *(const bf16x8*)(pkb + ((long)s << 9));
            while (1) {
                int sn = s + 56;
                bool more = sn < 512;
                bf16x8 pn;
                if (more) pn = *(const bf16x8*)(pkb + ((long)sn << 9));
                float acc;
                acc  = fast_tanh(q0.x + b2f((ushort)pv[0])) * w0.x;
                acc += fast_tanh(q0.y + b2f((ushort)pv[1])) * w0.y;
                acc += fast_tanh(q0.z + b2f((ushort)pv[2])) * w0.z;
                acc += fast_tanh(q0.w + b2f((ushort)pv[3])) * w0.w;
                acc += fast_tanh(q1.x + b2f((ushort)pv[4])) * w1.x;
                acc += fast_tanh(q1.y + b2f((ushort)pv[5])) * w1.y;
                acc += fast_tanh(q1.z + b2f((ushort)pv[6])) * w1.z;
                acc += fast_tanh(q1.w + b2f((ushort)pv[7])) * w1.w;
#pragma unroll
                for (int off = 32; off; off >>= 1) acc += __shfl_xor(acc, off);
                if (lane == 0) {
                    int i = (b << 9) + s;
                    cstoref(P.e + i, (P.mask[i] != 0) ? acc : -1e9f);
                }
                if (!more) break;
                s = sn; pv = pn;
            }
        } else if (bid < 992) {
            int b3 = bid - 896, kc = b3 / 24, nt = b3 % 24;
            gemm64x64<false, true, true>(P.h_b, P.Whh, As, Bs, 512, 512, kc * 128, kc * 128 + 128,
                                         P.gh, nullptr, 1536, 0, (long)nt * 64);
        }
        gridbar(P.bar);

        // ---- phase C: softmax + context. block -> (b = bid>>4, dc = bid&15) ----
        {
            int b  = bid >> 4;
            int dc = bid & 15;
            float* alpha = smem;            // 512
            float* wred  = smem + 512;      // 4
            float* part  = smem + 516;      // 256 (fallback only)
            float p0 = __expf(cloadf(P.e + (b << 9) + tid));
            float p1 = __expf(cloadf(P.e + (b << 9) + 256 + tid));
            alpha[tid] = p0; alpha[tid + 256] = p1;
            float wsum = p0 + p1;
#pragma unroll
            for (int off = 32; off; off >>= 1) wsum += __shfl_xor(wsum, off);
            if (lane == 0) wred[tid >> 6] = wsum;
            __syncthreads();
            float inv = 1.f / (wred[0] + wred[1] + wred[2] + wred[3]);
            if (P.useb) {
                int d   = tid >> 2;       // 0..63
                int qtr = tid & 3;        // s-quarter
                const ushort* pe = P.enc_t + (((long)b * 1024 + (dc << 6) + d) << 9) + (qtr << 7);
                const float* al = alpha + (qtr << 7);
                float acc = 0.f;
#pragma unroll
                for (int i = 0; i < 16; i++) {
                    bf16x8 v = *(const bf16x8*)(pe + i * 8);
                    acc += al[i*8+0] * b2f((ushort)v[0]) + al[i*8+1] * b2f((ushort)v[1])
                         + al[i*8+2] * b2f((ushort)v[2]) + al[i*8+3] * b2f((ushort)v[3])
                         + al[i*8+4] * b2f((ushort)v[4]) + al[i*8+5] * b2f((ushort)v[5])
                         + al[i*8+6] * b2f((ushort)v[6]) + al[i*8+7] * b2f((ushort)v[7]);
                }
                acc += __shfl_xor(acc, 1);
                acc += __shfl_xor(acc, 2);
                if (qtr == 0) {
                    ushort cb = f2b(acc * inv);
                    int dg = (dc << 6) + d;
                    cstoreu(P.xcat + b * 1280 + 256 + dg, cb);
                    cstoreu(P.cat2 + b * 1792 + 768 + dg, cb);
                }
                if (dc < 4 && tid < 64) {
                    ushort xv = f2b(P.trg[((long)b * 128 + t) * 256 + (dc << 6) + tid]);
                    cstoreu(P.xcat + b * 1280 + (dc << 6) + tid, xv);
                    cstoreu(P.cat2 + b * 1792 + (dc << 6) + tid, xv);
                }
            } else {
                int dl = lane, sr = tid >> 6;
                int d = (dc << 6) + dl;
                const float* pf = P.enc + ((long)b << 19) + d;
                float a0 = 0.f, a1 = 0.f, a2 = 0.f, a3 = 0.f;
                for (int s = sr; s < 512; s += 16) {
                    a0 += alpha[s]      * pf[(long)s << 10];
                    a1 += alpha[s + 4]  * pf[(long)(s + 4) << 10];
                    a2 += alpha[s + 8]  * pf[(long)(s + 8) << 10];
                    a3 += alpha[s + 12] * pf[(long)(s + 12) << 10];
                }
                part[tid] = (a0 + a1) + (a2 + a3);
                __syncthreads();
                if (sr == 0) {
                    float ctx = (part[dl] + part[64 + dl] + part[128 + dl] + part[192 + dl]) * inv;
                    ushort cb = f2b(ctx);
                    cstoreu(P.xcat + b * 1280 + 256 + d, cb);
                    cstoreu(P.cat2 + b * 1792 + 768 + d, cb);
                } else if (sr == 1 && dc < 4) {
                    ushort xv = f2b(P.trg[((long)b * 128 + t) * 256 + (dc << 6) + dl]);
                    cstoreu(P.xcat + b * 1280 + (dc << 6) + dl, xv);
                    cstoreu(P.cat2 + b * 1792 + (dc << 6) + dl, xv);
                }
            }
        }
        gridbar(P.bar);

        // ---- phase D: gx = [x_t, ctx] @ W_ih^T (192 blocks, K-split 8x160) ----
        if (bid < 192) {
            int kc = bid / 24, nt = bid % 24;
            gemm64x64<false, true, true>(P.xcat, P.Wih, As, Bs, 1280, 1280, kc * 160, kc * 160 + 160,
                                         P.gx, nullptr, 1536, 0, (long)nt * 64);
        }
        gridbar(P.bar);

        // ---- phase E: GRU gates + h update + re-zero accumulators ----
        if (bid < 128) {
            int b = idx >> 9, j = idx & 511;
            float* gxp = P.gx + b * 1536;
            float* ghp = P.gh + b * 1536;
            float rx = cloadf(gxp + j)        + P.bih[j];
            float zx = cloadf(gxp + j + 512)  + P.bih[j + 512];
            float nx = cloadf(gxp + j + 1024) + P.bih[j + 1024];
            float rh = cloadf(ghp + j)        + P.bhh[j];
            float zh = cloadf(ghp + j + 512)  + P.bhh[j + 512];
            float nh = cloadf(ghp + j + 1024) + P.bhh[j + 1024];
            float r = 1.f / (1.f + __expf(-(rx + rh)));
            float z = 1.f / (1.f + __expf(-(zx + zh)));
            float n = fast_tanh(nx + r * nh);
            float hn = (1.f - z) * n + z * hreg;
            hreg = hn;
            uint hb = (uint)f2b(hn);
            uint prt = __shfl_xor(hb, 1);
            if (!(lane & 1)) {
                uint w = hb | (prt << 16);
                cstore((uint*)(P.h_b + (idx & ~1)), w);
                cstore((uint*)(P.cat2 + b * 1792 + 256 + (j & ~1)), w);
            }
            P.d_states[((long)b * 128 + t) * 512 + j] = hn;   // pure output
            cstoref(gxp + j, 0.f); cstoref(gxp + j + 512, 0.f); cstoref(gxp + j + 1024, 0.f);
            cstoref(ghp + j, 0.f); cstoref(ghp + j + 512, 0.f); cstoref(ghp + j + 1024, 0.f);
            cstoref(P.q + idx, 0.f);
            cstoref(P.out_pre + ((long)b * 128 + t) * 512 + j, 0.f);
        }
        gridbar(P.bar);
    }

    // final pre-output GEMM for slice t=127 + hidden output
    if (bid < 64) {
        int kc = bid >> 3, nt = bid & 7;
        gemm64x64<false, true, true>(P.cat2, P.Wpre, As, Bs, 1792, 1792, kc * 224, kc * 224 + 224,
                                     P.out_pre + (long)127 * 512, nullptr, 65536, 0, (long)nt * 64);
    }
    if (bid < 128) P.out_hidden[idx] = hreg;
}

// bridge tanh + zero-init accumulators and barrier state.
__global__ void btanh_kernel(const float* __restrict__ br, const float* __restrict__ bbr,
                             float* __restrict__ h, ushort* __restrict__ h_b,
                             float* __restrict__ q, float* __restrict__ gh,
                             float* __restrict__ gx, int* __restrict__ bar)
{
    int idx = blockIdx.x * blockDim.x + threadIdx.x;  // 0..32767
    if (idx < 1024) bar[idx] = 0;
    int b = idx >> 9, j = idx & 511;
    float v = fast_tanh(br[idx] + bbr[j]);
    h[idx] = v;
    h_b[idx] = f2b(v);
    q[idx] = 0.f;
    gh[b * 1536 + j] = 0.f; gh[b * 1536 + j + 512] = 0.f; gh[b * 1536 + j + 1024] = 0.f;
    gx[b * 1536 + j] = 0.f; gx[b * 1536 + j + 512] = 0.f; gx[b * 1536 + j + 1024] = 0.f;
}

extern "C" void kernel_launch(void* const* d_in, const int* in_sizes, int n_in,
                              void* d_out, int out_size, void* d_ws, size_t ws_size,
                              hipStream_t stream)
{
    (void)in_sizes; (void)n_in; (void)out_size;
    const float* trg  = (const float*)d_in[0];
    const float* enc  = (const float*)d_in[1];
    const float* encF = (const float*)d_in[2];
    const int*   mask = (const int*)d_in[3];
    const float* Wkey = (const float*)d_in[4];
    const float* Wq   = (const float*)d_in[5];
    const float* wE   = (const float*)d_in[6];
    const float* Wbr  = (const float*)d_in[7];
    const float* bbr  = (const float*)d_in[8];
    const float* Wih  = (const float*)d_in[9];
    const float* Whh  = (const float*)d_in[10];
    const float* bih  = (const float*)d_in[11];
    const float* bhh  = (const float*)d_in[12];
    const float* Wpre = (const float*)d_in[13];

    char* p = (char*)d_ws;
    auto alloc = [&](size_t bytes) { void* r = (void*)p; p += (bytes + 255) & ~(size_t)255; return r; };
    ushort* pk     = (ushort*)alloc(16777216ul * 2);
    ushort* Wkey_b = (ushort*)alloc(524288ul * 2);
    ushort* Wq_b   = (ushort*)alloc(262144ul * 2);
    ushort* Wbr_b  = (ushort*)alloc(524288ul * 2);
    ushort* Wih_b  = (ushort*)alloc(1966080ul * 2);
    ushort* Whh_b  = (ushort*)alloc(786432ul * 2);
    ushort* Wpre_b = (ushort*)alloc(917504ul * 2);
    float*  h    = (float*)alloc(32768ul * 4);
    ushort* h_b  = (ushort*)alloc(32768ul * 2);
    float*  br   = (float*)alloc(32768ul * 4);
    float*  q    = (float*)alloc(32768ul * 4);
    float*  gh   = (float*)alloc(98304ul * 4);
    float*  gx   = (float*)alloc(98304ul * 4);
    float*  e    = (float*)alloc(32768ul * 4);
    ushort* xcat = (ushort*)alloc(81920ul * 2);
    ushort* cat2 = (ushort*)alloc(114688ul * 2);
    int*    bar  = (int*)alloc(1024ul * 4);
    size_t used = (size_t)(p - (char*)d_ws);
    int useb = (used + 33554432ul * 2 <= ws_size) ? 1 : 0;
    ushort* enc_t = useb ? (ushort*)alloc(33554432ul * 2) : nullptr;

    float* out_states = (float*)d_out;
    float* out_hidden = out_states + 64l * 128 * 512;
    float* out_pre    = out_hidden + 64l * 512;

    f2b4_kernel<<<512, 256, 0, stream>>>((const float4*)Wkey, (ushort4*)Wkey_b, 131072);
    f2b4_kernel<<<256, 256, 0, stream>>>((const float4*)Wq,   (ushort4*)Wq_b,   65536);
    f2b4_kernel<<<512, 256, 0, stream>>>((const float4*)Wbr,  (ushort4*)Wbr_b,  131072);
    f2b4_kernel<<<1920, 256, 0, stream>>>((const float4*)Wih, (ushort4*)Wih_b,  491520);
    f2b4_kernel<<<768, 256, 0, stream>>>((const float4*)Whh,  (ushort4*)Whh_b,  196608);
    f2b4_kernel<<<896, 256, 0, stream>>>((const float4*)Wpre, (ushort4*)Wpre_b, 229376);

    // pk = enc @ Wkey^T (A fp32 path) ; enc_t = transpose(enc) in bf16
    gemm_nt<true><<<4096, 256, 0, stream>>>(enc, Wkey_b, nullptr, pk, 1024, 1024, 512, 1024, 8);
    if (useb) tr_kernel<<<8192, 256, 0, stream>>>(enc, enc_t);

    gemm_nt<true><<<8, 256, 0, stream>>>(encF, Wbr_b, br, nullptr, 1024, 1024, 512, 1024, 8);
    btanh_kernel<<<128, 256, 0, stream>>>(br, bbr, h, h_b, q, gh, gx, bar);

    LP P;
    P.pk = pk; P.Wq = Wq_b; P.Whh = Whh_b; P.Wpre = Wpre_b; P.Wih = Wih_b;
    P.wE = wE; P.mask = mask; P.trg = trg; P.enc = enc; P.enc_t = enc_t;
    P.q = q; P.gh = gh; P.gx = gx; P.e = e;
    P.xcat = xcat; P.cat2 = cat2; P.h_b = h_b; P.h = h;
    P.bih = bih; P.bhh = bhh;
    P.d_states = out_states; P.out_pre = out_pre; P.out_hidden = out_hidden;
    P.bar = bar; P.useb = useb;
    loop_kernel<<<1024, 256, 0, stream>>>(P);
}